// Round 7
// baseline (1213.062 us; speedup 1.0000x reference)
//
#include <hip/hip_runtime.h>
#include <hip/hip_bf16.h>

#define N_   100000
#define E_   3200000
#define IN_  128
#define H_   256
#define OUT_ 256
#define G_   64
#define EPSV 1e-5f

#define NMT   1563            // ceil(N/64) M-tiles; gemm block id g: mt=g>>2, ct=g&3
#define NGEMM (NMT*4)         // 6252
#define NBKT  256
#define BW_   391             // bucket width: 256*391 >= N
#define EB_   1563            // edges per passB block (2048*1563 >= E)
#define CNTB  2048            // count grid-stride blocks
#define PBB   2048            // passB blocks
#define PCB   256             // passC blocks
#define G0G   1600            // gemm ids [0,1600) in K0
#define G1G   1600            // gemm ids [1600,3200) in K1
#define G2G   3052            // gemm ids [3200,6252) in K2

__device__ __forceinline__ unsigned short f2bf(float x){
  unsigned u = __float_as_uint(x);
  return (unsigned short)((u + 0x7FFFu + ((u >> 16) & 1u)) >> 16);
}
__device__ __forceinline__ float bf2f(unsigned short u){
  return __uint_as_float(((unsigned)u) << 16);
}

// ---------------- prefix-sum of degrees ----------------
__global__ __launch_bounds__(1024) void k_scan1(const int* __restrict__ deg, int* __restrict__ rowp,
                                                int* __restrict__ bsums){
  __shared__ int s[1024];
  int t = threadIdx.x;
  int i = blockIdx.x*1024 + t;
  int v = (i < N_) ? (deg[i] + 1) : 0;   // +1 = self loop
  s[t] = v;
  __syncthreads();
  for (int o = 1; o < 1024; o <<= 1){
    int x = (t >= o) ? s[t-o] : 0;
    __syncthreads();
    s[t] += x;
    __syncthreads();
  }
  if (i < N_) rowp[i+1] = s[t];
  if (t == 1023) bsums[blockIdx.x] = s[1023];
}

__global__ void k_scan2(int* __restrict__ bsums, int nb){
  __shared__ int s[128];
  int t = threadIdx.x;
  int v = (t < nb) ? bsums[t] : 0;
  s[t] = v;
  __syncthreads();
  for (int o = 1; o < 128; o <<= 1){
    int x = (t >= o) ? s[t-o] : 0;
    __syncthreads();
    s[t] += x;
    __syncthreads();
  }
  if (t < nb) bsums[t] = s[t] - v;       // exclusive
}

__global__ __launch_bounds__(1024) void k_scan3(int* __restrict__ rowp, const int* __restrict__ bsums){
  int t = threadIdx.x;
  int i = blockIdx.x*1024 + t;
  if (i < N_) rowp[i+1] += bsums[blockIdx.x];
  if (i == 0) rowp[0] = 0;
}

// bucket bases in staging: bcur[b] = rowp[lo] - lo  (edges-only offset)
__global__ void k_prepb(const int* __restrict__ rowp, int* __restrict__ bcur){
  int b = threadIdx.x;
  int lo = min(b*BW_, N_);
  bcur[b] = rowp[lo] - lo;
}

// ---------------- shared GEMM tile body ----------------
template<int K, bool BNIN>
__device__ __forceinline__ void gemm_tile(float (*As)[68], float (*Ws)[68],
                                          const float* __restrict__ A, const float* __restrict__ W,
                                          unsigned short* __restrict__ hb, int nrows,
                                          const float* __restrict__ a_s, const float* __restrict__ a_d,
                                          float* __restrict__ ssrc, float* __restrict__ sdst,
                                          const float* __restrict__ bnsc, const float* __restrict__ bnsh,
                                          int bx, int by, int t){
  const int bm = bx * 64;
  const int bn = by * 64;
  const int lm = t >> 2,  lk = (t & 3) * 4;    // A staging
  const int wk = t >> 4,  wn = (t & 15) * 4;   // W staging
  const int tm = (t >> 4) * 4, tn = (t & 15) * 4; // compute tile
  float acc[4][4];
  #pragma unroll
  for (int i=0;i<4;i++){
    #pragma unroll
    for (int j=0;j<4;j++) acc[i][j]=0.f;
  }
  for (int kb = 0; kb < K; kb += 16){
    const int arow = bm + lm;
    float4 av = make_float4(0.f,0.f,0.f,0.f);
    if (arow < nrows){
      av = *reinterpret_cast<const float4*>(A + (size_t)arow*K + kb + lk);
      if (BNIN){
        const float4 sc = *reinterpret_cast<const float4*>(bnsc + kb + lk);
        const float4 sh = *reinterpret_cast<const float4*>(bnsh + kb + lk);
        av.x = fmaxf(av.x*sc.x + sh.x, 0.f);
        av.y = fmaxf(av.y*sc.y + sh.y, 0.f);
        av.z = fmaxf(av.z*sc.z + sh.z, 0.f);
        av.w = fmaxf(av.w*sc.w + sh.w, 0.f);
      }
    }
    const float4 wv = *reinterpret_cast<const float4*>(W + (size_t)(kb + wk)*256 + bn + wn);
    __syncthreads();
    As[lk+0][lm]=av.x; As[lk+1][lm]=av.y; As[lk+2][lm]=av.z; As[lk+3][lm]=av.w;
    *reinterpret_cast<float4*>(&Ws[wk][wn]) = wv;
    __syncthreads();
    #pragma unroll
    for (int k=0;k<16;k++){
      const float4 a  = *reinterpret_cast<const float4*>(&As[k][tm]);
      const float4 bv = *reinterpret_cast<const float4*>(&Ws[k][tn]);
      acc[0][0]+=a.x*bv.x; acc[0][1]+=a.x*bv.y; acc[0][2]+=a.x*bv.z; acc[0][3]+=a.x*bv.w;
      acc[1][0]+=a.y*bv.x; acc[1][1]+=a.y*bv.y; acc[1][2]+=a.y*bv.z; acc[1][3]+=a.y*bv.w;
      acc[2][0]+=a.z*bv.x; acc[2][1]+=a.z*bv.y; acc[2][2]+=a.z*bv.z; acc[2][3]+=a.z*bv.w;
      acc[3][0]+=a.w*bv.x; acc[3][1]+=a.w*bv.y; acc[3][2]+=a.w*bv.z; acc[3][3]+=a.w*bv.w;
    }
  }
  #pragma unroll
  for (int i=0;i<4;i++){
    const int row = bm + tm + i;
    if (row < nrows){
      ushort4 o;
      o.x = f2bf(acc[i][0]); o.y = f2bf(acc[i][1]);
      o.z = f2bf(acc[i][2]); o.w = f2bf(acc[i][3]);
      *reinterpret_cast<ushort4*>(hb + (size_t)row*256 + bn + tn) = o;
    }
  }
  const float4 asv = *reinterpret_cast<const float4*>(a_s + bn + tn);
  const float4 adv = *reinterpret_cast<const float4*>(a_d + bn + tn);
  #pragma unroll
  for (int i=0;i<4;i++){
    float ps = acc[i][0]*asv.x + acc[i][1]*asv.y + acc[i][2]*asv.z + acc[i][3]*asv.w;
    float pd = acc[i][0]*adv.x + acc[i][1]*adv.y + acc[i][2]*adv.z + acc[i][3]*adv.w;
    #pragma unroll
    for (int o=1;o<16;o<<=1){ ps += __shfl_xor(ps, o, 64); pd += __shfl_xor(pd, o, 64); }
    if ((t & 15) == 0){
      const int row = bm + tm + i;
      if (row < nrows){ atomicAdd(&ssrc[row], ps); atomicAdd(&sdst[row], pd); }
    }
  }
}

// ---------------- K0: gemm1(part A) + degree count ----------------
__global__ __launch_bounds__(256) void k_g1_count(const float* __restrict__ A, const float* __restrict__ W,
                                                  unsigned short* __restrict__ hb,
                                                  const float* __restrict__ a_s, const float* __restrict__ a_d,
                                                  float* __restrict__ ssrc, float* __restrict__ sdst,
                                                  const int* __restrict__ ei, int* __restrict__ deg){
  __shared__ float As[16][68];
  __shared__ float Ws[16][68];
  const int bid = blockIdx.x;
  int aux = -1, g = -1;
  if (bid < 2*G0G){ if (bid & 1) aux = bid >> 1; else g = bid >> 1; }
  else aux = G0G + (bid - 2*G0G);
  if (g >= 0){
    gemm_tile<IN_,false>(As, Ws, A, W, hb, N_, a_s, a_d, ssrc, sdst, nullptr, nullptr,
                         g >> 2, g & 3, threadIdx.x);
    return;
  }
  const int stride = CNTB*256;
  for (int e = aux*256 + threadIdx.x; e < E_; e += stride)
    atomicAdd(&deg[ei[E_ + e]], 1);
}

// ---------------- K1: gemm1(part B) + passB bucket partition ----------------
__global__ __launch_bounds__(256) void k_g1_pb(const float* __restrict__ A, const float* __restrict__ W,
                                               unsigned short* __restrict__ hb,
                                               const float* __restrict__ a_s, const float* __restrict__ a_d,
                                               float* __restrict__ ssrc, float* __restrict__ sdst,
                                               const int* __restrict__ ei, int* __restrict__ bcur,
                                               uint2* __restrict__ staging){
  __shared__ float As[16][68];
  __shared__ float Ws[16][68];
  __shared__ int hist[NBKT];
  const int bid = blockIdx.x;
  const int t = threadIdx.x;
  int aux = -1, g = -1;
  if (bid < 2*G1G){ if (bid & 1) aux = bid >> 1; else g = bid >> 1; }
  else aux = G1G + (bid - 2*G1G);
  if (g >= 0){
    const int gg = G0G + g;
    gemm_tile<IN_,false>(As, Ws, A, W, hb, N_, a_s, a_d, ssrc, sdst, nullptr, nullptr,
                         gg >> 2, gg & 3, t);
    return;
  }
  // passB: partition edges [e0,e1) into 256 dst-buckets in staging
  hist[t] = 0;
  __syncthreads();
  const int e0 = aux*EB_;
  const int e1 = min(e0 + EB_, E_);
  for (int e = e0 + t; e < e1; e += 256)
    atomicAdd(&hist[ei[E_ + e] / BW_], 1);
  __syncthreads();
  const int h = hist[t];
  int gb = 0;
  if (h > 0) gb = atomicAdd(&bcur[t], h);
  __syncthreads();
  hist[t] = gb;
  __syncthreads();
  for (int e = e0 + t; e < e1; e += 256){
    const int s = ei[e], d = ei[E_ + e];
    const int pos = atomicAdd(&hist[d / BW_], 1);
    staging[pos] = make_uint2((unsigned)s, (unsigned)d);
  }
}

// ---------------- K2: gemm1(part C) + passC in-bucket CSR fill ----------------
__global__ __launch_bounds__(256) void k_g1_pc(const float* __restrict__ A, const float* __restrict__ W,
                                               unsigned short* __restrict__ hb,
                                               const float* __restrict__ a_s, const float* __restrict__ a_d,
                                               float* __restrict__ ssrc, float* __restrict__ sdst,
                                               const uint2* __restrict__ staging, const int* __restrict__ rowp,
                                               int* __restrict__ col){
  __shared__ float As[16][68];
  __shared__ float Ws[16][68];
  __shared__ int cur[BW_];
  __shared__ int rw[BW_+1];
  const int bid = blockIdx.x;
  const int t = threadIdx.x;
  const int c = bid / 12;
  if (!((bid % 12 == 0) && c < PCB)){
    const int g = 2*G0G/2 + G1G + (bid - min(c + 1, PCB));  // 3200 + local
    gemm_tile<IN_,false>(As, Ws, A, W, hb, N_, a_s, a_d, ssrc, sdst, nullptr, nullptr,
                         g >> 2, g & 3, t);
    return;
  }
  // passC: bucket c covers nodes [lo,hi)
  const int lo = c*BW_;
  const int hi = min(lo + BW_, N_);
  const int nn = hi - lo;
  for (int j = t; j <= nn; j += 256) rw[j] = rowp[lo + j];
  __syncthreads();
  for (int j = t; j < nn; j += 256){
    cur[j] = 1;
    col[rw[j]] = lo + j;        // self loop in slot 0
  }
  const int base  = rw[0] - lo;
  const int base1 = rw[nn] - hi;
  __syncthreads();
  for (int i = base + t; i < base1; i += 256){
    const uint2 p = staging[i];
    const int d = (int)p.y;
    const int r = atomicAdd(&cur[d - lo], 1);
    col[rw[d - lo] + r] = (int)p.x;
  }
}

// layer-2 GEMM (BN1+relu fused on A-load), 2D grid
template<int K, bool BNIN>
__global__ __launch_bounds__(256) void k_gemm(const float* __restrict__ A, const float* __restrict__ W,
                                              unsigned short* __restrict__ hb, int nrows,
                                              const float* __restrict__ a_s, const float* __restrict__ a_d,
                                              float* __restrict__ ssrc, float* __restrict__ sdst,
                                              const float* __restrict__ bnsc, const float* __restrict__ bnsh){
  __shared__ float As[16][68];
  __shared__ float Ws[16][68];
  gemm_tile<K,BNIN>(As, Ws, A, W, hb, nrows, a_s, a_d, ssrc, sdst, bnsc, bnsh,
                    blockIdx.x, blockIdx.y, threadIdx.x);
}

// ---------------- GAT aggregation (R5 structure) + fused BN stats ----------------
__global__ __launch_bounds__(256) void k_agg(const unsigned short* __restrict__ hb, const int* __restrict__ col,
                                             const int* __restrict__ rowp, const float* __restrict__ ssrc,
                                             const float* __restrict__ sdst, const float* __restrict__ bias,
                                             float* __restrict__ out, float* __restrict__ bnsum,
                                             float* __restrict__ bnsq){
  __shared__ float sbn[512];
  __shared__ __align__(16) float2 wsb[4][64];   // (w, bits(src)) per wave
  const int t = threadIdx.x;
  sbn[t] = 0.f; sbn[t+256] = 0.f;
  const int lane = t & 63;
  const int wid  = t >> 6;
  const int fo = lane*4;
  const float4 bb = *reinterpret_cast<const float4*>(bias + fo);
  float s0=0.f,s1=0.f,s2=0.f,s3=0.f, q0=0.f,q1=0.f,q2=0.f,q3=0.f;
  __syncthreads();
  for (int node = blockIdx.x*4 + wid; node < N_; node += gridDim.x*4){
    const int start = rowp[node];
    const int end   = rowp[node+1];
    const float sd  = sdst[node];
    float den_l = 0.f;
    float ax=0.f, ay=0.f, az=0.f, aw=0.f;
    float bx=0.f, by=0.f, bz=0.f, bw=0.f;
    for (int base = start; base < end; base += 64){
      const int p = base + lane;
      float w = 0.f; int s = 0;
      if (p < end){
        s = col[p];
        float e = ssrc[s] + sd;
        e = e > 0.f ? e : 0.2f*e;
        w = expf(e);
      }
      den_l += w;
      wsb[wid][lane] = make_float2(w, __int_as_float(s));
      const int m = (end - base < 64) ? (end - base) : 64;
      int j = 0;
      for (; j + 2 <= m; j += 2){
        const float4 q = *reinterpret_cast<const float4*>(&wsb[wid][j]);
        const float w0 = q.x; const int v0 = __float_as_int(q.y);
        const float w1 = q.z; const int v1 = __float_as_int(q.w);
        const ushort4 h0 = *reinterpret_cast<const ushort4*>(hb + (size_t)v0*256 + fo);
        const ushort4 h1 = *reinterpret_cast<const ushort4*>(hb + (size_t)v1*256 + fo);
        ax += w0*bf2f(h0.x); ay += w0*bf2f(h0.y); az += w0*bf2f(h0.z); aw += w0*bf2f(h0.w);
        bx += w1*bf2f(h1.x); by += w1*bf2f(h1.y); bz += w1*bf2f(h1.z); bw += w1*bf2f(h1.w);
      }
      if (j < m){
        const float2 q = wsb[wid][j];
        const float w0 = q.x; const int v0 = __float_as_int(q.y);
        const ushort4 h0 = *reinterpret_cast<const ushort4*>(hb + (size_t)v0*256 + fo);
        ax += w0*bf2f(h0.x); ay += w0*bf2f(h0.y); az += w0*bf2f(h0.z); aw += w0*bf2f(h0.w);
      }
    }
    float den = den_l;
    #pragma unroll
    for (int o = 32; o; o >>= 1) den += __shfl_xor(den, o, 64);
    const float inv = 1.f/den;
    float4 r;
    r.x = (ax+bx)*inv + bb.x;
    r.y = (ay+by)*inv + bb.y;
    r.z = (az+bz)*inv + bb.z;
    r.w = (aw+bw)*inv + bb.w;
    *reinterpret_cast<float4*>(out + (size_t)node*256 + fo) = r;
    s0 += r.x; s1 += r.y; s2 += r.z; s3 += r.w;
    q0 += r.x*r.x; q1 += r.y*r.y; q2 += r.z*r.z; q3 += r.w*r.w;
  }
  atomicAdd(&sbn[fo+0], s0); atomicAdd(&sbn[fo+1], s1);
  atomicAdd(&sbn[fo+2], s2); atomicAdd(&sbn[fo+3], s3);
  atomicAdd(&sbn[256+fo+0], q0); atomicAdd(&sbn[256+fo+1], q1);
  atomicAdd(&sbn[256+fo+2], q2); atomicAdd(&sbn[256+fo+3], q3);
  __syncthreads();
  atomicAdd(&bnsum[t], sbn[t]);
  atomicAdd(&bnsq[t],  sbn[256+t]);
}

__global__ void k_bnprep(const float* __restrict__ g, const float* __restrict__ be,
                         float* __restrict__ bsum, float* __restrict__ bsq){
  const int f = threadIdx.x;
  const float mean = bsum[f] * (1.0f/N_);
  const float var  = bsq[f]  * (1.0f/N_) - mean*mean;
  const float sc = g[f] / sqrtf(var + EPSV);
  bsum[f] = sc;
  bsq[f]  = be[f] - mean*sc;
}

// ---------------- global mean pool (fused BN2+relu) ----------------
__global__ __launch_bounds__(256) void k_pool(const float* __restrict__ x, const int* __restrict__ batch,
                                              const float* __restrict__ sc, const float* __restrict__ sh,
                                              float* __restrict__ psum, float* __restrict__ pcnt){
  const int f = threadIdx.x;
  const float scf = sc[f], shf = sh[f];
  const int RPB = (N_ + gridDim.x - 1) / gridDim.x;
  const int r0 = blockIdx.x * RPB;
  const int r1 = min(r0 + RPB, N_);
  if (r0 >= N_) return;
  float local = 0.f, c = 0.f;
  int curg = -1;
  for (int r = r0; r < r1; ++r){
    const int g = batch[r];
    if (g != curg){
      if (curg >= 0){
        atomicAdd(&psum[curg*256 + f], local);
        if (f == 0) atomicAdd(&pcnt[curg], c);
      }
      curg = g; local = 0.f; c = 0.f;
    }
    local += fmaxf(x[(size_t)r*256 + f]*scf + shf, 0.f);
    c += 1.f;
  }
  if (curg >= 0){
    atomicAdd(&psum[curg*256 + f], local);
    if (f == 0) atomicAdd(&pcnt[curg], c);
  }
}

// ---------------- FC head ----------------
__global__ __launch_bounds__(256) void k_fc1(const float* __restrict__ psum, const float* __restrict__ pcnt,
                                             const float* __restrict__ w, const float* __restrict__ b,
                                             float* __restrict__ z){
  __shared__ float p[256];
  const int g = blockIdx.x, f = threadIdx.x;
  const float cnt = fmaxf(pcnt[g], 1.f);
  p[f] = psum[g*256 + f] / cnt;
  __syncthreads();
  float acc = b[f];
  #pragma unroll 8
  for (int k = 0; k < 256; ++k) acc += p[k] * w[k*256 + f];
  z[g*256 + f] = fmaxf(acc, 0.f);
}

__global__ __launch_bounds__(128) void k_fc2(const float* __restrict__ zin, const float* __restrict__ w,
                                             const float* __restrict__ b, float* __restrict__ z){
  __shared__ float p[256];
  const int g = blockIdx.x, f = threadIdx.x;
  p[f] = zin[g*256 + f];
  p[f+128] = zin[g*256 + f + 128];
  __syncthreads();
  float acc = b[f];
  #pragma unroll 8
  for (int k = 0; k < 256; ++k) acc += p[k] * w[k*128 + f];
  z[g*128 + f] = fmaxf(acc, 0.f);
}

__global__ __launch_bounds__(64) void k_fc3(const float* __restrict__ zin, const float* __restrict__ w,
                                            const float* __restrict__ b, float* __restrict__ out){
  const int g = threadIdx.x;   // 64 graphs
  float acc = b[0];
  #pragma unroll 8
  for (int k = 0; k < 128; ++k) acc += zin[g*128 + k] * w[k];
  out[g] = acc;
}

// ---------------- launch ----------------
extern "C" void kernel_launch(void* const* d_in, const int* in_sizes, int n_in,
                              void* d_out, int out_size, void* d_ws, size_t ws_size,
                              hipStream_t stream){
  (void)in_sizes; (void)n_in; (void)out_size; (void)ws_size;
  const float* x    = (const float*)d_in[0];
  const float* W1   = (const float*)d_in[1];
  const float* a_s1 = (const float*)d_in[2];
  const float* a_d1 = (const float*)d_in[3];
  const float* b1   = (const float*)d_in[4];
  const float* g1   = (const float*)d_in[5];
  const float* be1  = (const float*)d_in[6];
  const float* W2   = (const float*)d_in[7];
  const float* a_s2 = (const float*)d_in[8];
  const float* a_d2 = (const float*)d_in[9];
  const float* b2   = (const float*)d_in[10];
  const float* g2   = (const float*)d_in[11];
  const float* be2  = (const float*)d_in[12];
  const float* fc1w = (const float*)d_in[13];
  const float* fc1b = (const float*)d_in[14];
  const float* fc2w = (const float*)d_in[15];
  const float* fc2b = (const float*)d_in[16];
  const float* fc3w = (const float*)d_in[17];
  const float* fc3b = (const float*)d_in[18];
  const int*   ei   = (const int*)d_in[19];
  const int*   batch= (const int*)d_in[20];
  float* out = (float*)d_out;

  char* ws = (char*)d_ws;
  size_t off = 0;
  auto alloc = [&](size_t bytes)->char*{
    char* p = ws + off;
    off += (bytes + 255) & ~(size_t)255;
    return p;
  };
  unsigned short* hb = (unsigned short*)alloc((size_t)N_*256*2);  // bf16 h (both layers)
  float* agg    = (float*)alloc((size_t)N_*256*4);
  uint2* staging= (uint2*)alloc((size_t)E_*8);
  int*   col    = (int*)  alloc((size_t)(E_+N_)*4);
  int*   rowp   = (int*)  alloc((size_t)(N_+1)*4);
  int*   deg    = (int*)  alloc((size_t)N_*4);
  int*   bcur   = (int*)  alloc(NBKT*4);
  float* ssrc   = (float*)alloc((size_t)N_*4);
  float* sdst   = (float*)alloc((size_t)N_*4);
  float* bns1   = (float*)alloc(512*4);
  float* bns2   = (float*)alloc(512*4);
  float* pooled = (float*)alloc((G_*256 + G_)*4);
  float* z1     = (float*)alloc(G_*256*4);
  float* z2     = (float*)alloc(G_*128*4);
  int*   bsums  = (int*)  alloc(1024*4);

  const int NCHUNK = (N_ + 1023) / 1024;   // 98

  // ---- K0: gemm1 part A + degree count ----
  hipMemsetAsync(deg, 0, (size_t)N_*4, stream);
  hipMemsetAsync(ssrc, 0, (size_t)N_*4, stream);
  hipMemsetAsync(sdst, 0, (size_t)N_*4, stream);
  hipMemsetAsync(bns1, 0, 512*4, stream);
  k_g1_count<<<2*G0G + (CNTB - G0G), 256, 0, stream>>>(x, W1, hb, a_s1, a_d1, ssrc, sdst, ei, deg);

  // ---- scans + bucket bases ----
  k_scan1<<<NCHUNK, 1024, 0, stream>>>(deg, rowp, bsums);
  k_scan2<<<1, 128, 0, stream>>>(bsums, NCHUNK);
  k_scan3<<<NCHUNK, 1024, 0, stream>>>(rowp, bsums);
  k_prepb<<<1, NBKT, 0, stream>>>(rowp, bcur);

  // ---- K1: gemm1 part B + bucket partition ----
  k_g1_pb<<<2*G1G + (PBB - G1G), 256, 0, stream>>>(x, W1, hb, a_s1, a_d1, ssrc, sdst, ei, bcur, staging);

  // ---- K2: gemm1 part C + in-bucket CSR fill ----
  k_g1_pc<<<G2G + PCB, 256, 0, stream>>>(x, W1, hb, a_s1, a_d1, ssrc, sdst, staging, rowp, col);

  // ---- layer 1 aggregation (+BN1 stats) ----
  k_agg<<<2048, 256, 0, stream>>>(hb, col, rowp, ssrc, sdst, b1, agg, bns1, bns1 + 256);
  k_bnprep<<<1, 256, 0, stream>>>(g1, be1, bns1, bns1 + 256);

  // ---- layer 2 (BN1+relu fused into GEMM A-load) ----
  hipMemsetAsync(ssrc, 0, (size_t)N_*4, stream);
  hipMemsetAsync(sdst, 0, (size_t)N_*4, stream);
  hipMemsetAsync(bns2, 0, 512*4, stream);
  k_gemm<H_, true><<<dim3(NMT, 4), 256, 0, stream>>>(agg, W2, hb, N_, a_s2, a_d2, ssrc, sdst, bns1, bns1 + 256);
  k_agg<<<2048, 256, 0, stream>>>(hb, col, rowp, ssrc, sdst, b2, agg, bns2, bns2 + 256);
  k_bnprep<<<1, 256, 0, stream>>>(g2, be2, bns2, bns2 + 256);

  // ---- pool (BN2+relu fused) + head ----
  hipMemsetAsync(pooled, 0, (size_t)(G_*256 + G_)*4, stream);
  k_pool<<<512, 256, 0, stream>>>(agg, batch, bns2, bns2 + 256, pooled, pooled + G_*256);
  k_fc1<<<G_, 256, 0, stream>>>(pooled, pooled + G_*256, fc1w, fc1b, z1);
  k_fc2<<<G_, 128, 0, stream>>>(z1, fc2w, fc2b, z2);
  k_fc3<<<1, 64, 0, stream>>>(z2, fc3w, fc3b, out);
}

// Round 8
// 1171.627 us; speedup vs baseline: 1.0354x; 1.0354x over previous
//
#include <hip/hip_runtime.h>
#include <hip/hip_bf16.h>

#define N_   100000
#define E_   3200000
#define IN_  128
#define H_   256
#define OUT_ 256
#define G_   64
#define EPSV 1e-5f

#define NMT   1563            // ceil(N/64) M-tiles; 4 col tiles -> 6252 gemm1 blocks
#define EB2   1563            // edges per aux block (2048*1563 >= E)
#define AUXN  2048
#define G0N   2000            // gemm1 ids in K0
#define G1N   2100            // gemm1 ids in K1
#define G2N   2152            // gemm1 ids in K2

__device__ __forceinline__ unsigned short f2bf(float x){
  unsigned u = __float_as_uint(x);
  return (unsigned short)((u + 0x7FFFu + ((u >> 16) & 1u)) >> 16);
}
__device__ __forceinline__ float bf2f(unsigned short u){
  return __uint_as_float(((unsigned)u) << 16);
}

// ---------------- scans ----------------
__global__ __launch_bounds__(1024) void k_scan1(const int* __restrict__ deg, int* __restrict__ rowp,
                                                int* __restrict__ bsums){
  __shared__ int s[1024];
  int t = threadIdx.x;
  int i = blockIdx.x*1024 + t;
  int v = (i < N_) ? (deg[i] + 1) : 0;   // +1 = self loop
  s[t] = v;
  __syncthreads();
  for (int o = 1; o < 1024; o <<= 1){
    int x = (t >= o) ? s[t-o] : 0;
    __syncthreads();
    s[t] += x;
    __syncthreads();
  }
  if (i < N_) rowp[i+1] = s[t];
  if (t == 1023) bsums[blockIdx.x] = s[1023];
}

__global__ void k_scan2(int* __restrict__ bsums, int nb){
  __shared__ int s[128];
  int t = threadIdx.x;
  int v = (t < nb) ? bsums[t] : 0;
  s[t] = v;
  __syncthreads();
  for (int o = 1; o < 128; o <<= 1){
    int x = (t >= o) ? s[t-o] : 0;
    __syncthreads();
    s[t] += x;
    __syncthreads();
  }
  if (t < nb) bsums[t] = s[t] - v;       // exclusive
}

// finalize rowp; pre-place self-loops (sequential col writes); cursor -> first edge slot
__global__ __launch_bounds__(1024) void k_scan3(const int* __restrict__ deg, int* __restrict__ rowp,
                                                const int* __restrict__ bsums, int* __restrict__ cursor,
                                                int* __restrict__ col){
  int t = threadIdx.x;
  int i = blockIdx.x*1024 + t;
  if (i < N_){
    int rp = rowp[i+1] + bsums[blockIdx.x];
    rowp[i+1] = rp;
    int start = rp - (deg[i] + 1);
    cursor[i] = start + 1;
    col[start] = i;                     // self loop in slot 0
  }
  if (i == 0) rowp[0] = 0;
}

// bucket bases in staging: bcur[b] = rowp[lo] - lo  (edges-only prefix at bucket boundary)
__global__ void k_prepb(const int* __restrict__ rowp, int* __restrict__ bcur){
  int b = threadIdx.x;
  if (b < 98){
    int lo = min(b << 10, N_);
    bcur[b] = rowp[lo] - lo;
  }
}

// ---------------- shared GEMM tile body (64x64, R5-proven) ----------------
template<int K, bool BNIN>
__device__ __forceinline__ void gemm_tile(float (*As)[68], float (*Ws)[68],
                                          const float* __restrict__ A, const float* __restrict__ W,
                                          unsigned short* __restrict__ hb, int nrows,
                                          const float* __restrict__ a_s, const float* __restrict__ a_d,
                                          float* __restrict__ ssrc, float* __restrict__ sdst,
                                          const float* __restrict__ bnsc, const float* __restrict__ bnsh,
                                          int bx, int by, int t){
  const int bm = bx * 64;
  const int bn = by * 64;
  const int lm = t >> 2,  lk = (t & 3) * 4;
  const int wk = t >> 4,  wn = (t & 15) * 4;
  const int tm = (t >> 4) * 4, tn = (t & 15) * 4;
  float acc[4][4];
  #pragma unroll
  for (int i=0;i<4;i++){
    #pragma unroll
    for (int j=0;j<4;j++) acc[i][j]=0.f;
  }
  for (int kb = 0; kb < K; kb += 16){
    const int arow = bm + lm;
    float4 av = make_float4(0.f,0.f,0.f,0.f);
    if (arow < nrows){
      av = *reinterpret_cast<const float4*>(A + (size_t)arow*K + kb + lk);
      if (BNIN){
        const float4 sc = *reinterpret_cast<const float4*>(bnsc + kb + lk);
        const float4 sh = *reinterpret_cast<const float4*>(bnsh + kb + lk);
        av.x = fmaxf(av.x*sc.x + sh.x, 0.f);
        av.y = fmaxf(av.y*sc.y + sh.y, 0.f);
        av.z = fmaxf(av.z*sc.z + sh.z, 0.f);
        av.w = fmaxf(av.w*sc.w + sh.w, 0.f);
      }
    }
    const float4 wv = *reinterpret_cast<const float4*>(W + (size_t)(kb + wk)*256 + bn + wn);
    __syncthreads();
    As[lk+0][lm]=av.x; As[lk+1][lm]=av.y; As[lk+2][lm]=av.z; As[lk+3][lm]=av.w;
    *reinterpret_cast<float4*>(&Ws[wk][wn]) = wv;
    __syncthreads();
    #pragma unroll
    for (int k=0;k<16;k++){
      const float4 a  = *reinterpret_cast<const float4*>(&As[k][tm]);
      const float4 bv = *reinterpret_cast<const float4*>(&Ws[k][tn]);
      acc[0][0]+=a.x*bv.x; acc[0][1]+=a.x*bv.y; acc[0][2]+=a.x*bv.z; acc[0][3]+=a.x*bv.w;
      acc[1][0]+=a.y*bv.x; acc[1][1]+=a.y*bv.y; acc[1][2]+=a.y*bv.z; acc[1][3]+=a.y*bv.w;
      acc[2][0]+=a.z*bv.x; acc[2][1]+=a.z*bv.y; acc[2][2]+=a.z*bv.z; acc[2][3]+=a.z*bv.w;
      acc[3][0]+=a.w*bv.x; acc[3][1]+=a.w*bv.y; acc[3][2]+=a.w*bv.z; acc[3][3]+=a.w*bv.w;
    }
  }
  #pragma unroll
  for (int i=0;i<4;i++){
    const int row = bm + tm + i;
    if (row < nrows){
      ushort4 o;
      o.x = f2bf(acc[i][0]); o.y = f2bf(acc[i][1]);
      o.z = f2bf(acc[i][2]); o.w = f2bf(acc[i][3]);
      *reinterpret_cast<ushort4*>(hb + (size_t)row*256 + bn + tn) = o;
    }
  }
  const float4 asv = *reinterpret_cast<const float4*>(a_s + bn + tn);
  const float4 adv = *reinterpret_cast<const float4*>(a_d + bn + tn);
  #pragma unroll
  for (int i=0;i<4;i++){
    float ps = acc[i][0]*asv.x + acc[i][1]*asv.y + acc[i][2]*asv.z + acc[i][3]*asv.w;
    float pd = acc[i][0]*adv.x + acc[i][1]*adv.y + acc[i][2]*adv.z + acc[i][3]*adv.w;
    #pragma unroll
    for (int o=1;o<16;o<<=1){ ps += __shfl_xor(ps, o, 64); pd += __shfl_xor(pd, o, 64); }
    if ((t & 15) == 0){
      const int row = bm + tm + i;
      if (row < nrows){ atomicAdd(&ssrc[row], ps); atomicAdd(&sdst[row], pd); }
    }
  }
}

// id split helper: alternate gemm/aux for the first 2*min, leftover is whichever is larger
__device__ __forceinline__ void split_ids(int bid, int GN, int& g, int& aux){
  g = -1; aux = -1;
  const int nmin = (GN < AUXN) ? GN : AUXN;
  if (bid < 2*nmin){ if (bid & 1) aux = bid >> 1; else g = bid >> 1; }
  else {
    int r = bid - 2*nmin;
    if (GN > AUXN) g = AUXN + r; else aux = GN + r;
  }
}

// ---------------- K0: gemm1 part A + degree count ----------------
__global__ __launch_bounds__(256) void k_g1_count(const float* __restrict__ A, const float* __restrict__ W,
                                                  unsigned short* __restrict__ hb,
                                                  const float* __restrict__ a_s, const float* __restrict__ a_d,
                                                  float* __restrict__ ssrc, float* __restrict__ sdst,
                                                  const int* __restrict__ ei, int* __restrict__ deg){
  __shared__ float As[16][68];
  __shared__ float Ws[16][68];
  int g, aux;
  split_ids(blockIdx.x, G0N, g, aux);
  if (g >= 0){
    gemm_tile<IN_,false>(As, Ws, A, W, hb, N_, a_s, a_d, ssrc, sdst, nullptr, nullptr,
                         g % NMT, g / NMT, threadIdx.x);
    return;
  }
  const int stride = AUXN*256;
  for (int e = aux*256 + threadIdx.x; e < E_; e += stride)
    atomicAdd(&deg[ei[E_ + e]], 1);
}

// ---------------- K1: gemm1 part B + LDS-binned bucket partition ----------------
__global__ __launch_bounds__(256) void k_g1_pb(const float* __restrict__ A, const float* __restrict__ W,
                                               unsigned short* __restrict__ hb,
                                               const float* __restrict__ a_s, const float* __restrict__ a_d,
                                               float* __restrict__ ssrc, float* __restrict__ sdst,
                                               const int* __restrict__ ei, int* __restrict__ bcur,
                                               uint2* __restrict__ staging){
  __shared__ __align__(16) char um[14040];   // union: gemm tiles (8704) | passB structures
  const int t = threadIdx.x;
  int g, aux;
  split_ids(blockIdx.x, G1N, g, aux);
  if (g >= 0){
    float (*As)[68] = reinterpret_cast<float(*)[68]>(um);
    float (*Ws)[68] = reinterpret_cast<float(*)[68]>(um + 4352);
    const int gg = G0N + g;
    gemm_tile<IN_,false>(As, Ws, A, W, hb, N_, a_s, a_d, ssrc, sdst, nullptr, nullptr,
                         gg % NMT, gg / NMT, t);
    return;
  }
  uint2* slots = reinterpret_cast<uint2*>(um);          // 1563 * 8B = 12504
  int* hist  = reinterpret_cast<int*>(um + 12504);      // 128
  int* lbase = reinterpret_cast<int*>(um + 13016);      // 128
  int* cur2  = reinterpret_cast<int*>(um + 13528);      // 128
  const int e0 = aux*EB2;
  const int e1 = min(e0 + EB2, E_);
  if (t < 128) hist[t] = 0;
  __syncthreads();
  for (int e = e0 + t; e < e1; e += 256)
    atomicAdd(&hist[((unsigned)ei[E_ + e]) >> 10], 1);
  __syncthreads();
  if (t < 128) lbase[t] = hist[t];
  __syncthreads();
  for (int o = 1; o < 128; o <<= 1){
    int x = (t >= o && t < 128) ? lbase[t-o] : 0;
    __syncthreads();
    if (t < 128) lbase[t] += x;
    __syncthreads();
  }
  int excl = 0;
  if (t < 128) excl = lbase[t] - hist[t];
  __syncthreads();
  if (t < 128){ lbase[t] = excl; cur2[t] = excl; }
  __syncthreads();
  for (int e = e0 + t; e < e1; e += 256){
    const int s = ei[e], d = ei[E_ + e];
    const int b = ((unsigned)d) >> 10;
    const int slot = atomicAdd(&cur2[b], 1);
    slots[slot] = make_uint2((unsigned)s, (unsigned)d);
  }
  __syncthreads();
  if (t < 128){
    const int c = cur2[t] - lbase[t];
    hist[t] = (c > 0) ? atomicAdd(&bcur[t], c) : 0;   // hist := global base
  }
  __syncthreads();
  const int total = e1 - e0;
  for (int i = t; i < total; i += 256){
    const uint2 u = slots[i];
    const int b = u.y >> 10;
    staging[hist[b] + (i - lbase[b])] = u;            // coalesced runs per bucket
  }
}

// ---------------- K2: gemm1 part C + bucket-major CSR fill (L2-local atomics) ----------------
__global__ __launch_bounds__(256) void k_g1_pc(const float* __restrict__ A, const float* __restrict__ W,
                                               unsigned short* __restrict__ hb,
                                               const float* __restrict__ a_s, const float* __restrict__ a_d,
                                               float* __restrict__ ssrc, float* __restrict__ sdst,
                                               const uint2* __restrict__ staging, int* __restrict__ cursor,
                                               int* __restrict__ col){
  __shared__ float As[16][68];
  __shared__ float Ws[16][68];
  const int t = threadIdx.x;
  int g, aux;
  split_ids(blockIdx.x, G2N, g, aux);
  if (g >= 0){
    const int gg = G0N + G1N + g;
    gemm_tile<IN_,false>(As, Ws, A, W, hb, N_, a_s, a_d, ssrc, sdst, nullptr, nullptr,
                         gg % NMT, gg / NMT, t);
    return;
  }
  const int i0 = aux*EB2;
  const int i1 = min(i0 + EB2, E_);
  for (int i = i0 + t; i < i1; i += 256){
    const uint2 u = staging[i];
    const int pos = atomicAdd(&cursor[u.y], 1);
    col[pos] = (int)u.x;
  }
}

// layer-2 GEMM (BN1+relu fused on A-load), 2D grid
template<int K, bool BNIN>
__global__ __launch_bounds__(256) void k_gemm(const float* __restrict__ A, const float* __restrict__ W,
                                              unsigned short* __restrict__ hb, int nrows,
                                              const float* __restrict__ a_s, const float* __restrict__ a_d,
                                              float* __restrict__ ssrc, float* __restrict__ sdst,
                                              const float* __restrict__ bnsc, const float* __restrict__ bnsh){
  __shared__ float As[16][68];
  __shared__ float Ws[16][68];
  gemm_tile<K,BNIN>(As, Ws, A, W, hb, nrows, a_s, a_d, ssrc, sdst, bnsc, bnsh,
                    blockIdx.x, blockIdx.y, threadIdx.x);
}

// ---------------- GAT aggregation (R5-proven) + fused BN stats ----------------
__global__ __launch_bounds__(256) void k_agg(const unsigned short* __restrict__ hb, const int* __restrict__ col,
                                             const int* __restrict__ rowp, const float* __restrict__ ssrc,
                                             const float* __restrict__ sdst, const float* __restrict__ bias,
                                             float* __restrict__ out, float* __restrict__ bnsum,
                                             float* __restrict__ bnsq){
  __shared__ float sbn[512];
  __shared__ __align__(16) float2 wsb[4][64];
  const int t = threadIdx.x;
  sbn[t] = 0.f; sbn[t+256] = 0.f;
  const int lane = t & 63;
  const int wid  = t >> 6;
  const int fo = lane*4;
  const float4 bb = *reinterpret_cast<const float4*>(bias + fo);
  float s0=0.f,s1=0.f,s2=0.f,s3=0.f, q0=0.f,q1=0.f,q2=0.f,q3=0.f;
  __syncthreads();
  for (int node = blockIdx.x*4 + wid; node < N_; node += gridDim.x*4){
    const int start = rowp[node];
    const int end   = rowp[node+1];
    const float sd  = sdst[node];
    float den_l = 0.f;
    float ax=0.f, ay=0.f, az=0.f, aw=0.f;
    float bx=0.f, by=0.f, bz=0.f, bw=0.f;
    for (int base = start; base < end; base += 64){
      const int p = base + lane;
      float w = 0.f; int s = 0;
      if (p < end){
        s = col[p];
        float e = ssrc[s] + sd;
        e = e > 0.f ? e : 0.2f*e;
        w = expf(e);
      }
      den_l += w;
      wsb[wid][lane] = make_float2(w, __int_as_float(s));
      const int m = (end - base < 64) ? (end - base) : 64;
      int j = 0;
      for (; j + 2 <= m; j += 2){
        const float4 q = *reinterpret_cast<const float4*>(&wsb[wid][j]);
        const float w0 = q.x; const int v0 = __float_as_int(q.y);
        const float w1 = q.z; const int v1 = __float_as_int(q.w);
        const ushort4 h0 = *reinterpret_cast<const ushort4*>(hb + (size_t)v0*256 + fo);
        const ushort4 h1 = *reinterpret_cast<const ushort4*>(hb + (size_t)v1*256 + fo);
        ax += w0*bf2f(h0.x); ay += w0*bf2f(h0.y); az += w0*bf2f(h0.z); aw += w0*bf2f(h0.w);
        bx += w1*bf2f(h1.x); by += w1*bf2f(h1.y); bz += w1*bf2f(h1.z); bw += w1*bf2f(h1.w);
      }
      if (j < m){
        const float2 q = wsb[wid][j];
        const float w0 = q.x; const int v0 = __float_as_int(q.y);
        const ushort4 h0 = *reinterpret_cast<const ushort4*>(hb + (size_t)v0*256 + fo);
        ax += w0*bf2f(h0.x); ay += w0*bf2f(h0.y); az += w0*bf2f(h0.z); aw += w0*bf2f(h0.w);
      }
    }
    float den = den_l;
    #pragma unroll
    for (int o = 32; o; o >>= 1) den += __shfl_xor(den, o, 64);
    const float inv = 1.f/den;
    float4 r;
    r.x = (ax+bx)*inv + bb.x;
    r.y = (ay+by)*inv + bb.y;
    r.z = (az+bz)*inv + bb.z;
    r.w = (aw+bw)*inv + bb.w;
    *reinterpret_cast<float4*>(out + (size_t)node*256 + fo) = r;
    s0 += r.x; s1 += r.y; s2 += r.z; s3 += r.w;
    q0 += r.x*r.x; q1 += r.y*r.y; q2 += r.z*r.z; q3 += r.w*r.w;
  }
  atomicAdd(&sbn[fo+0], s0); atomicAdd(&sbn[fo+1], s1);
  atomicAdd(&sbn[fo+2], s2); atomicAdd(&sbn[fo+3], s3);
  atomicAdd(&sbn[256+fo+0], q0); atomicAdd(&sbn[256+fo+1], q1);
  atomicAdd(&sbn[256+fo+2], q2); atomicAdd(&sbn[256+fo+3], q3);
  __syncthreads();
  atomicAdd(&bnsum[t], sbn[t]);
  atomicAdd(&bnsq[t],  sbn[256+t]);
}

__global__ void k_bnprep(const float* __restrict__ g, const float* __restrict__ be,
                         float* __restrict__ bsum, float* __restrict__ bsq){
  const int f = threadIdx.x;
  const float mean = bsum[f] * (1.0f/N_);
  const float var  = bsq[f]  * (1.0f/N_) - mean*mean;
  const float sc = g[f] / sqrtf(var + EPSV);
  bsum[f] = sc;
  bsq[f]  = be[f] - mean*sc;
}

// ---------------- global mean pool (fused BN2+relu) ----------------
__global__ __launch_bounds__(256) void k_pool(const float* __restrict__ x, const int* __restrict__ batch,
                                              const float* __restrict__ sc, const float* __restrict__ sh,
                                              float* __restrict__ psum, float* __restrict__ pcnt){
  const int f = threadIdx.x;
  const float scf = sc[f], shf = sh[f];
  const int RPB = (N_ + gridDim.x - 1) / gridDim.x;
  const int r0 = blockIdx.x * RPB;
  const int r1 = min(r0 + RPB, N_);
  if (r0 >= N_) return;
  float local = 0.f, c = 0.f;
  int curg = -1;
  for (int r = r0; r < r1; ++r){
    const int g = batch[r];
    if (g != curg){
      if (curg >= 0){
        atomicAdd(&psum[curg*256 + f], local);
        if (f == 0) atomicAdd(&pcnt[curg], c);
      }
      curg = g; local = 0.f; c = 0.f;
    }
    local += fmaxf(x[(size_t)r*256 + f]*scf + shf, 0.f);
    c += 1.f;
  }
  if (curg >= 0){
    atomicAdd(&psum[curg*256 + f], local);
    if (f == 0) atomicAdd(&pcnt[curg], c);
  }
}

// ---------------- FC head ----------------
__global__ __launch_bounds__(256) void k_fc1(const float* __restrict__ psum, const float* __restrict__ pcnt,
                                             const float* __restrict__ w, const float* __restrict__ b,
                                             float* __restrict__ z){
  __shared__ float p[256];
  const int g = blockIdx.x, f = threadIdx.x;
  const float cnt = fmaxf(pcnt[g], 1.f);
  p[f] = psum[g*256 + f] / cnt;
  __syncthreads();
  float acc = b[f];
  #pragma unroll 8
  for (int k = 0; k < 256; ++k) acc += p[k] * w[k*256 + f];
  z[g*256 + f] = fmaxf(acc, 0.f);
}

__global__ __launch_bounds__(128) void k_fc2(const float* __restrict__ zin, const float* __restrict__ w,
                                             const float* __restrict__ b, float* __restrict__ z){
  __shared__ float p[256];
  const int g = blockIdx.x, f = threadIdx.x;
  p[f] = zin[g*256 + f];
  p[f+128] = zin[g*256 + f + 128];
  __syncthreads();
  float acc = b[f];
  #pragma unroll 8
  for (int k = 0; k < 256; ++k) acc += p[k] * w[k*128 + f];
  z[g*128 + f] = fmaxf(acc, 0.f);
}

__global__ __launch_bounds__(64) void k_fc3(const float* __restrict__ zin, const float* __restrict__ w,
                                            const float* __restrict__ b, float* __restrict__ out){
  const int g = threadIdx.x;   // 64 graphs
  float acc = b[0];
  #pragma unroll 8
  for (int k = 0; k < 128; ++k) acc += zin[g*128 + k] * w[k];
  out[g] = acc;
}

// ---------------- launch ----------------
extern "C" void kernel_launch(void* const* d_in, const int* in_sizes, int n_in,
                              void* d_out, int out_size, void* d_ws, size_t ws_size,
                              hipStream_t stream){
  (void)in_sizes; (void)n_in; (void)out_size; (void)ws_size;
  const float* x    = (const float*)d_in[0];
  const float* W1   = (const float*)d_in[1];
  const float* a_s1 = (const float*)d_in[2];
  const float* a_d1 = (const float*)d_in[3];
  const float* b1   = (const float*)d_in[4];
  const float* g1   = (const float*)d_in[5];
  const float* be1  = (const float*)d_in[6];
  const float* W2   = (const float*)d_in[7];
  const float* a_s2 = (const float*)d_in[8];
  const float* a_d2 = (const float*)d_in[9];
  const float* b2   = (const float*)d_in[10];
  const float* g2   = (const float*)d_in[11];
  const float* be2  = (const float*)d_in[12];
  const float* fc1w = (const float*)d_in[13];
  const float* fc1b = (const float*)d_in[14];
  const float* fc2w = (const float*)d_in[15];
  const float* fc2b = (const float*)d_in[16];
  const float* fc3w = (const float*)d_in[17];
  const float* fc3b = (const float*)d_in[18];
  const int*   ei   = (const int*)d_in[19];
  const int*   batch= (const int*)d_in[20];
  float* out = (float*)d_out;

  char* ws = (char*)d_ws;
  size_t off = 0;
  auto alloc = [&](size_t bytes)->char*{
    char* p = ws + off;
    off += (bytes + 255) & ~(size_t)255;
    return p;
  };
  unsigned short* hb = (unsigned short*)alloc((size_t)N_*256*2);
  float* agg    = (float*)alloc((size_t)N_*256*4);
  uint2* staging= (uint2*)alloc((size_t)E_*8);
  int*   col    = (int*)  alloc((size_t)(E_+N_)*4);
  int*   rowp   = (int*)  alloc((size_t)(N_+1)*4);
  int*   deg    = (int*)  alloc((size_t)N_*4);
  int*   cursor = (int*)  alloc((size_t)N_*4);
  int*   bcur   = (int*)  alloc(128*4);
  float* ssrc   = (float*)alloc((size_t)N_*4);
  float* sdst   = (float*)alloc((size_t)N_*4);
  float* bns1   = (float*)alloc(512*4);
  float* bns2   = (float*)alloc(512*4);
  float* pooled = (float*)alloc((G_*256 + G_)*4);
  float* z1     = (float*)alloc(G_*256*4);
  float* z2     = (float*)alloc(G_*128*4);
  int*   bsums  = (int*)  alloc(1024*4);

  const int NCHUNK = (N_ + 1023) / 1024;   // 98

  // ---- K0: gemm1 part A + degree count ----
  hipMemsetAsync(deg, 0, (size_t)N_*4, stream);
  hipMemsetAsync(ssrc, 0, (size_t)N_*4, stream);
  hipMemsetAsync(sdst, 0, (size_t)N_*4, stream);
  hipMemsetAsync(bns1, 0, 512*4, stream);
  k_g1_count<<<2*G0N + (AUXN - G0N), 256, 0, stream>>>(x, W1, hb, a_s1, a_d1, ssrc, sdst, ei, deg);

  // ---- scans (+ self-loop placement, cursor init, bucket bases) ----
  k_scan1<<<NCHUNK, 1024, 0, stream>>>(deg, rowp, bsums);
  k_scan2<<<1, 128, 0, stream>>>(bsums, NCHUNK);
  k_scan3<<<NCHUNK, 1024, 0, stream>>>(deg, rowp, bsums, cursor, col);
  k_prepb<<<1, 128, 0, stream>>>(rowp, bcur);

  // ---- K1: gemm1 part B + LDS-binned bucket partition ----
  k_g1_pb<<<2*AUXN + (G1N - AUXN), 256, 0, stream>>>(x, W1, hb, a_s1, a_d1, ssrc, sdst, ei, bcur, staging);

  // ---- K2: gemm1 part C + bucket-major fill ----
  k_g1_pc<<<2*AUXN + (G2N - AUXN), 256, 0, stream>>>(x, W1, hb, a_s1, a_d1, ssrc, sdst, staging, cursor, col);

  // ---- layer 1 aggregation (+BN1 stats) ----
  k_agg<<<2048, 256, 0, stream>>>(hb, col, rowp, ssrc, sdst, b1, agg, bns1, bns1 + 256);
  k_bnprep<<<1, 256, 0, stream>>>(g1, be1, bns1, bns1 + 256);

  // ---- layer 2 (BN1+relu fused into GEMM A-load) ----
  hipMemsetAsync(ssrc, 0, (size_t)N_*4, stream);
  hipMemsetAsync(sdst, 0, (size_t)N_*4, stream);
  hipMemsetAsync(bns2, 0, 512*4, stream);
  k_gemm<H_, true><<<dim3(NMT, 4), 256, 0, stream>>>(agg, W2, hb, N_, a_s2, a_d2, ssrc, sdst, bns1, bns1 + 256);
  k_agg<<<2048, 256, 0, stream>>>(hb, col, rowp, ssrc, sdst, b2, agg, bns2, bns2 + 256);
  k_bnprep<<<1, 256, 0, stream>>>(g2, be2, bns2, bns2 + 256);

  // ---- pool (BN2+relu fused) + head ----
  hipMemsetAsync(pooled, 0, (size_t)(G_*256 + G_)*4, stream);
  k_pool<<<512, 256, 0, stream>>>(agg, batch, bns2, bns2 + 256, pooled, pooled + G_*256);
  k_fc1<<<G_, 256, 0, stream>>>(pooled, pooled + G_*256, fc1w, fc1b, z1);
  k_fc2<<<G_, 128, 0, stream>>>(z1, fc2w, fc2b, z2);
  k_fc3<<<1, 64, 0, stream>>>(z2, fc3w, fc3b, out);
}

// Round 9
// 1083.200 us; speedup vs baseline: 1.1199x; 1.0816x over previous
//
#include <hip/hip_runtime.h>
#include <hip/hip_bf16.h>

#define N_   100000
#define E_   3200000
#define IN_  128
#define H_   256
#define OUT_ 256
#define G_   64
#define EPSV 1e-5f

#define NMT   1563            // ceil(N/64) M-tiles; 4 col tiles -> 6252 gemm1 blocks
#define EB2   1563            // edges per aux block (2048*1563 >= E)
#define AUXN  2048
#define G0N   2000            // gemm1 ids in K0
#define G1N   2100            // gemm1 ids in K1
#define G2N   2152            // gemm1 ids in K2

typedef short bf8v __attribute__((ext_vector_type(8)));
typedef float f32x4 __attribute__((ext_vector_type(4)));

__device__ __forceinline__ unsigned short f2bf(float x){
  unsigned u = __float_as_uint(x);
  return (unsigned short)((u + 0x7FFFu + ((u >> 16) & 1u)) >> 16);
}
__device__ __forceinline__ float bf2f(unsigned short u){
  return __uint_as_float(((unsigned)u) << 16);
}

// ---------------- scans ----------------
__global__ __launch_bounds__(1024) void k_scan1(const int* __restrict__ deg, int* __restrict__ rowp,
                                                int* __restrict__ bsums){
  __shared__ int s[1024];
  int t = threadIdx.x;
  int i = blockIdx.x*1024 + t;
  int v = (i < N_) ? (deg[i] + 1) : 0;   // +1 = self loop
  s[t] = v;
  __syncthreads();
  for (int o = 1; o < 1024; o <<= 1){
    int x = (t >= o) ? s[t-o] : 0;
    __syncthreads();
    s[t] += x;
    __syncthreads();
  }
  if (i < N_) rowp[i+1] = s[t];
  if (t == 1023) bsums[blockIdx.x] = s[1023];
}

__global__ void k_scan2(int* __restrict__ bsums, int nb){
  __shared__ int s[128];
  int t = threadIdx.x;
  int v = (t < nb) ? bsums[t] : 0;
  s[t] = v;
  __syncthreads();
  for (int o = 1; o < 128; o <<= 1){
    int x = (t >= o) ? s[t-o] : 0;
    __syncthreads();
    s[t] += x;
    __syncthreads();
  }
  if (t < nb) bsums[t] = s[t] - v;       // exclusive
}

// finalize rowp; pre-place self-loops; cursor -> first edge slot
__global__ __launch_bounds__(1024) void k_scan3(const int* __restrict__ deg, int* __restrict__ rowp,
                                                const int* __restrict__ bsums, int* __restrict__ cursor,
                                                int* __restrict__ col){
  int t = threadIdx.x;
  int i = blockIdx.x*1024 + t;
  if (i < N_){
    int rp = rowp[i+1] + bsums[blockIdx.x];
    rowp[i+1] = rp;
    int start = rp - (deg[i] + 1);
    cursor[i] = start + 1;
    col[start] = i;                     // self loop in slot 0
  }
  if (i == 0) rowp[0] = 0;
}

__global__ void k_prepb(const int* __restrict__ rowp, int* __restrict__ bcur){
  int b = threadIdx.x;
  if (b < 98){
    int lo = min(b << 10, N_);
    bcur[b] = rowp[lo] - lo;
  }
}

// W2 -> transposed split-bf16: Wt_hi/Wt_lo [n][k]
__global__ void k_prepw(const float* __restrict__ W, unsigned short* __restrict__ Wt_hi,
                        unsigned short* __restrict__ Wt_lo){
  const int k = blockIdx.x, n = threadIdx.x;
  const float v = W[k*256 + n];
  const unsigned short h = f2bf(v);
  const float r = v - bf2f(h);
  Wt_hi[n*256 + k] = h;
  Wt_lo[n*256 + k] = f2bf(r);
}

// ---------------- shared fp32 GEMM tile body (gemm1 / cover role) ----------------
template<int K, bool BNIN>
__device__ __forceinline__ void gemm_tile(float (*As)[68], float (*Ws)[68],
                                          const float* __restrict__ A, const float* __restrict__ W,
                                          unsigned short* __restrict__ hb, int nrows,
                                          const float* __restrict__ a_s, const float* __restrict__ a_d,
                                          float* __restrict__ ssrc, float* __restrict__ sdst,
                                          const float* __restrict__ bnsc, const float* __restrict__ bnsh,
                                          int bx, int by, int t){
  const int bm = bx * 64;
  const int bn = by * 64;
  const int lm = t >> 2,  lk = (t & 3) * 4;
  const int wk = t >> 4,  wn = (t & 15) * 4;
  const int tm = (t >> 4) * 4, tn = (t & 15) * 4;
  float acc[4][4];
  #pragma unroll
  for (int i=0;i<4;i++){
    #pragma unroll
    for (int j=0;j<4;j++) acc[i][j]=0.f;
  }
  for (int kb = 0; kb < K; kb += 16){
    const int arow = bm + lm;
    float4 av = make_float4(0.f,0.f,0.f,0.f);
    if (arow < nrows){
      av = *reinterpret_cast<const float4*>(A + (size_t)arow*K + kb + lk);
      if (BNIN){
        const float4 sc = *reinterpret_cast<const float4*>(bnsc + kb + lk);
        const float4 sh = *reinterpret_cast<const float4*>(bnsh + kb + lk);
        av.x = fmaxf(av.x*sc.x + sh.x, 0.f);
        av.y = fmaxf(av.y*sc.y + sh.y, 0.f);
        av.z = fmaxf(av.z*sc.z + sh.z, 0.f);
        av.w = fmaxf(av.w*sc.w + sh.w, 0.f);
      }
    }
    const float4 wv = *reinterpret_cast<const float4*>(W + (size_t)(kb + wk)*256 + bn + wn);
    __syncthreads();
    As[lk+0][lm]=av.x; As[lk+1][lm]=av.y; As[lk+2][lm]=av.z; As[lk+3][lm]=av.w;
    *reinterpret_cast<float4*>(&Ws[wk][wn]) = wv;
    __syncthreads();
    #pragma unroll
    for (int k=0;k<16;k++){
      const float4 a  = *reinterpret_cast<const float4*>(&As[k][tm]);
      const float4 bv = *reinterpret_cast<const float4*>(&Ws[k][tn]);
      acc[0][0]+=a.x*bv.x; acc[0][1]+=a.x*bv.y; acc[0][2]+=a.x*bv.z; acc[0][3]+=a.x*bv.w;
      acc[1][0]+=a.y*bv.x; acc[1][1]+=a.y*bv.y; acc[1][2]+=a.y*bv.z; acc[1][3]+=a.y*bv.w;
      acc[2][0]+=a.z*bv.x; acc[2][1]+=a.z*bv.y; acc[2][2]+=a.z*bv.z; acc[2][3]+=a.z*bv.w;
      acc[3][0]+=a.w*bv.x; acc[3][1]+=a.w*bv.y; acc[3][2]+=a.w*bv.z; acc[3][3]+=a.w*bv.w;
    }
  }
  #pragma unroll
  for (int i=0;i<4;i++){
    const int row = bm + tm + i;
    if (row < nrows){
      ushort4 o;
      o.x = f2bf(acc[i][0]); o.y = f2bf(acc[i][1]);
      o.z = f2bf(acc[i][2]); o.w = f2bf(acc[i][3]);
      *reinterpret_cast<ushort4*>(hb + (size_t)row*256 + bn + tn) = o;
    }
  }
  const float4 asv = *reinterpret_cast<const float4*>(a_s + bn + tn);
  const float4 adv = *reinterpret_cast<const float4*>(a_d + bn + tn);
  #pragma unroll
  for (int i=0;i<4;i++){
    float ps = acc[i][0]*asv.x + acc[i][1]*asv.y + acc[i][2]*asv.z + acc[i][3]*asv.w;
    float pd = acc[i][0]*adv.x + acc[i][1]*adv.y + acc[i][2]*adv.z + acc[i][3]*adv.w;
    #pragma unroll
    for (int o=1;o<16;o<<=1){ ps += __shfl_xor(ps, o, 64); pd += __shfl_xor(pd, o, 64); }
    if ((t & 15) == 0){
      const int row = bm + tm + i;
      if (row < nrows){ atomicAdd(&ssrc[row], ps); atomicAdd(&sdst[row], pd); }
    }
  }
}

__device__ __forceinline__ void split_ids(int bid, int GN, int& g, int& aux){
  g = -1; aux = -1;
  const int nmin = (GN < AUXN) ? GN : AUXN;
  if (bid < 2*nmin){ if (bid & 1) aux = bid >> 1; else g = bid >> 1; }
  else {
    int r = bid - 2*nmin;
    if (GN > AUXN) g = AUXN + r; else aux = GN + r;
  }
}

// ---------------- K0: gemm1 part A + degree count ----------------
__global__ __launch_bounds__(256) void k_g1_count(const float* __restrict__ A, const float* __restrict__ W,
                                                  unsigned short* __restrict__ hb,
                                                  const float* __restrict__ a_s, const float* __restrict__ a_d,
                                                  float* __restrict__ ssrc, float* __restrict__ sdst,
                                                  const int* __restrict__ ei, int* __restrict__ deg){
  __shared__ float As[16][68];
  __shared__ float Ws[16][68];
  int g, aux;
  split_ids(blockIdx.x, G0N, g, aux);
  if (g >= 0){
    gemm_tile<IN_,false>(As, Ws, A, W, hb, N_, a_s, a_d, ssrc, sdst, nullptr, nullptr,
                         g % NMT, g / NMT, threadIdx.x);
    return;
  }
  const int stride = AUXN*256;
  for (int e = aux*256 + threadIdx.x; e < E_; e += stride)
    atomicAdd(&deg[ei[E_ + e]], 1);
}

// ---------------- K1: gemm1 part B + LDS-binned bucket partition ----------------
__global__ __launch_bounds__(256) void k_g1_pb(const float* __restrict__ A, const float* __restrict__ W,
                                               unsigned short* __restrict__ hb,
                                               const float* __restrict__ a_s, const float* __restrict__ a_d,
                                               float* __restrict__ ssrc, float* __restrict__ sdst,
                                               const int* __restrict__ ei, int* __restrict__ bcur,
                                               uint2* __restrict__ staging){
  __shared__ __align__(16) char um[14040];
  const int t = threadIdx.x;
  int g, aux;
  split_ids(blockIdx.x, G1N, g, aux);
  if (g >= 0){
    float (*As)[68] = reinterpret_cast<float(*)[68]>(um);
    float (*Ws)[68] = reinterpret_cast<float(*)[68]>(um + 4352);
    const int gg = G0N + g;
    gemm_tile<IN_,false>(As, Ws, A, W, hb, N_, a_s, a_d, ssrc, sdst, nullptr, nullptr,
                         gg % NMT, gg / NMT, t);
    return;
  }
  uint2* slots = reinterpret_cast<uint2*>(um);
  int* hist  = reinterpret_cast<int*>(um + 12504);
  int* lbase = reinterpret_cast<int*>(um + 13016);
  int* cur2  = reinterpret_cast<int*>(um + 13528);
  const int e0 = aux*EB2;
  const int e1 = min(e0 + EB2, E_);
  if (t < 128) hist[t] = 0;
  __syncthreads();
  for (int e = e0 + t; e < e1; e += 256)
    atomicAdd(&hist[((unsigned)ei[E_ + e]) >> 10], 1);
  __syncthreads();
  if (t < 128) lbase[t] = hist[t];
  __syncthreads();
  for (int o = 1; o < 128; o <<= 1){
    int x = (t >= o && t < 128) ? lbase[t-o] : 0;
    __syncthreads();
    if (t < 128) lbase[t] += x;
    __syncthreads();
  }
  int excl = 0;
  if (t < 128) excl = lbase[t] - hist[t];
  __syncthreads();
  if (t < 128){ lbase[t] = excl; cur2[t] = excl; }
  __syncthreads();
  for (int e = e0 + t; e < e1; e += 256){
    const int s = ei[e], d = ei[E_ + e];
    const int b = ((unsigned)d) >> 10;
    const int slot = atomicAdd(&cur2[b], 1);
    slots[slot] = make_uint2((unsigned)s, (unsigned)d);
  }
  __syncthreads();
  if (t < 128){
    const int c = cur2[t] - lbase[t];
    hist[t] = (c > 0) ? atomicAdd(&bcur[t], c) : 0;
  }
  __syncthreads();
  const int total = e1 - e0;
  for (int i = t; i < total; i += 256){
    const uint2 u = slots[i];
    const int b = u.y >> 10;
    staging[hist[b] + (i - lbase[b])] = u;
  }
}

// ---------------- K2: gemm1 part C + bucket-major CSR fill ----------------
__global__ __launch_bounds__(256) void k_g1_pc(const float* __restrict__ A, const float* __restrict__ W,
                                               unsigned short* __restrict__ hb,
                                               const float* __restrict__ a_s, const float* __restrict__ a_d,
                                               float* __restrict__ ssrc, float* __restrict__ sdst,
                                               const uint2* __restrict__ staging, int* __restrict__ cursor,
                                               int* __restrict__ col){
  __shared__ float As[16][68];
  __shared__ float Ws[16][68];
  const int t = threadIdx.x;
  int g, aux;
  split_ids(blockIdx.x, G2N, g, aux);
  if (g >= 0){
    const int gg = G0N + G1N + g;
    gemm_tile<IN_,false>(As, Ws, A, W, hb, N_, a_s, a_d, ssrc, sdst, nullptr, nullptr,
                         gg % NMT, gg / NMT, t);
    return;
  }
  const int i0 = aux*EB2;
  const int i1 = min(i0 + EB2, E_);
  for (int i = i0 + t; i < i1; i += 256){
    const uint2 u = staging[i];
    const int pos = atomicAdd(&cursor[u.y], 1);
    col[pos] = (int)u.x;
  }
}

// ---------------- gemm2: split-bf16 MFMA (D = A·W2, BN1+relu fused on A) ----------------
// Operand swap: A-op = W^T fragments (n rows, k-contig), B-op = act(A) fragments (m cols).
// D[n'][m']: col=lane&15 -> m, row regs -> 4 consecutive n -> coalesced ushort4 C-stores.
__global__ __launch_bounds__(256) void k_gemm2_mfma(const float* __restrict__ A,
                                                    const unsigned short* __restrict__ Wt_hi,
                                                    const unsigned short* __restrict__ Wt_lo,
                                                    unsigned short* __restrict__ hb,
                                                    const float* __restrict__ a_s, const float* __restrict__ a_d,
                                                    float* __restrict__ ssrc, float* __restrict__ sdst,
                                                    const float* __restrict__ bnsc, const float* __restrict__ bnsh){
  __shared__ short As_hi[64][40];   // 80B rows (16B-aligned, bank-spread)
  __shared__ short As_lo[64][40];
  const int t = threadIdx.x;
  const int lane = t & 63;
  const int w = t >> 6;             // wave -> n-slice [w*64, w*64+64)
  const int l15 = lane & 15;
  const int lk  = lane >> 4;        // k-group 0..3
  const int m0 = blockIdx.x * 64;
  const int srow = t >> 2;          // staging row 0..63
  const int skq  = (t & 3) * 8;     // staging k offset 0/8/16/24
  f32x4 acc[4][4];
  #pragma unroll
  for (int fm=0; fm<4; fm++)
    #pragma unroll
    for (int fn=0; fn<4; fn++) acc[fm][fn] = (f32x4)0.f;
  float4 asv[4], adv[4];
  #pragma unroll
  for (int fn=0; fn<4; fn++){
    asv[fn] = *reinterpret_cast<const float4*>(a_s + w*64 + fn*16 + lk*4);
    adv[fn] = *reinterpret_cast<const float4*>(a_d + w*64 + fn*16 + lk*4);
  }
  const int arow = m0 + srow;
  for (int kb = 0; kb < 256; kb += 32){
    // stage act(A) chunk [64][32] -> hi/lo bf16
    float v[8];
    if (arow < N_){
      const float4 x0 = *reinterpret_cast<const float4*>(A + (size_t)arow*256 + kb + skq);
      const float4 x1 = *reinterpret_cast<const float4*>(A + (size_t)arow*256 + kb + skq + 4);
      const float4 s0 = *reinterpret_cast<const float4*>(bnsc + kb + skq);
      const float4 s1 = *reinterpret_cast<const float4*>(bnsc + kb + skq + 4);
      const float4 h0 = *reinterpret_cast<const float4*>(bnsh + kb + skq);
      const float4 h1 = *reinterpret_cast<const float4*>(bnsh + kb + skq + 4);
      v[0]=fmaxf(x0.x*s0.x+h0.x,0.f); v[1]=fmaxf(x0.y*s0.y+h0.y,0.f);
      v[2]=fmaxf(x0.z*s0.z+h0.z,0.f); v[3]=fmaxf(x0.w*s0.w+h0.w,0.f);
      v[4]=fmaxf(x1.x*s1.x+h1.x,0.f); v[5]=fmaxf(x1.y*s1.y+h1.y,0.f);
      v[6]=fmaxf(x1.z*s1.z+h1.z,0.f); v[7]=fmaxf(x1.w*s1.w+h1.w,0.f);
    } else {
      #pragma unroll
      for (int j=0;j<8;j++) v[j]=0.f;
    }
    unsigned hh[4], ll[4];
    #pragma unroll
    for (int j=0;j<4;j++){
      const unsigned short ha = f2bf(v[2*j]),   hb_ = f2bf(v[2*j+1]);
      const unsigned short la = f2bf(v[2*j]   - bf2f(ha));
      const unsigned short lb = f2bf(v[2*j+1] - bf2f(hb_));
      hh[j] = (unsigned)ha | ((unsigned)hb_ << 16);
      ll[j] = (unsigned)la | ((unsigned)lb << 16);
    }
    __syncthreads();   // protect previous iteration's reads
    *reinterpret_cast<uint4*>(&As_hi[srow][skq]) = make_uint4(hh[0],hh[1],hh[2],hh[3]);
    *reinterpret_cast<uint4*>(&As_lo[srow][skq]) = make_uint4(ll[0],ll[1],ll[2],ll[3]);
    __syncthreads();
    // W-side fragments straight from global (L2-resident 256KB)
    bf8v afh[4], afl[4];
    #pragma unroll
    for (int fn=0; fn<4; fn++){
      const size_t nrow = (size_t)(w*64 + fn*16 + l15);
      afh[fn] = *reinterpret_cast<const bf8v*>(Wt_hi + nrow*256 + kb + lk*8);
      afl[fn] = *reinterpret_cast<const bf8v*>(Wt_lo + nrow*256 + kb + lk*8);
    }
    #pragma unroll
    for (int fm=0; fm<4; fm++){
      const bf8v bh = *reinterpret_cast<const bf8v*>(&As_hi[fm*16 + l15][lk*8]);
      const bf8v bl = *reinterpret_cast<const bf8v*>(&As_lo[fm*16 + l15][lk*8]);
      #pragma unroll
      for (int fn=0; fn<4; fn++){
        acc[fm][fn] = __builtin_amdgcn_mfma_f32_16x16x32_bf16(afh[fn], bh, acc[fm][fn], 0,0,0);
        acc[fm][fn] = __builtin_amdgcn_mfma_f32_16x16x32_bf16(afl[fn], bh, acc[fm][fn], 0,0,0);
        acc[fm][fn] = __builtin_amdgcn_mfma_f32_16x16x32_bf16(afh[fn], bl, acc[fm][fn], 0,0,0);
      }
    }
  }
  // epilogue: C store (bf16) + fused score dots
  #pragma unroll
  for (int fm=0; fm<4; fm++){
    const int m = m0 + fm*16 + l15;
    float ps = 0.f, pd = 0.f;
    #pragma unroll
    for (int fn=0; fn<4; fn++){
      const f32x4 c = acc[fm][fn];
      ps += c[0]*asv[fn].x + c[1]*asv[fn].y + c[2]*asv[fn].z + c[3]*asv[fn].w;
      pd += c[0]*adv[fn].x + c[1]*adv[fn].y + c[2]*adv[fn].z + c[3]*adv[fn].w;
      if (m < N_){
        ushort4 o;
        o.x = f2bf(c[0]); o.y = f2bf(c[1]); o.z = f2bf(c[2]); o.w = f2bf(c[3]);
        *reinterpret_cast<ushort4*>(hb + (size_t)m*256 + w*64 + fn*16 + lk*4) = o;
      }
    }
    ps += __shfl_xor(ps, 16, 64); ps += __shfl_xor(ps, 32, 64);
    pd += __shfl_xor(pd, 16, 64); pd += __shfl_xor(pd, 32, 64);
    if (lk == 0 && m < N_){
      atomicAdd(&ssrc[m], ps);
      atomicAdd(&sdst[m], pd);
    }
  }
}

// ---------------- GAT aggregation (R5-proven) + fused BN stats ----------------
__global__ __launch_bounds__(256) void k_agg(const unsigned short* __restrict__ hb, const int* __restrict__ col,
                                             const int* __restrict__ rowp, const float* __restrict__ ssrc,
                                             const float* __restrict__ sdst, const float* __restrict__ bias,
                                             float* __restrict__ out, float* __restrict__ bnsum,
                                             float* __restrict__ bnsq){
  __shared__ float sbn[512];
  __shared__ __align__(16) float2 wsb[4][64];
  const int t = threadIdx.x;
  sbn[t] = 0.f; sbn[t+256] = 0.f;
  const int lane = t & 63;
  const int wid  = t >> 6;
  const int fo = lane*4;
  const float4 bb = *reinterpret_cast<const float4*>(bias + fo);
  float s0=0.f,s1=0.f,s2=0.f,s3=0.f, q0=0.f,q1=0.f,q2=0.f,q3=0.f;
  __syncthreads();
  for (int node = blockIdx.x*4 + wid; node < N_; node += gridDim.x*4){
    const int start = rowp[node];
    const int end   = rowp[node+1];
    const float sd  = sdst[node];
    float den_l = 0.f;
    float ax=0.f, ay=0.f, az=0.f, aw=0.f;
    float bx=0.f, by=0.f, bz=0.f, bw=0.f;
    for (int base = start; base < end; base += 64){
      const int p = base + lane;
      float w = 0.f; int s = 0;
      if (p < end){
        s = col[p];
        float e = ssrc[s] + sd;
        e = e > 0.f ? e : 0.2f*e;
        w = expf(e);
      }
      den_l += w;
      wsb[wid][lane] = make_float2(w, __int_as_float(s));
      const int m = (end - base < 64) ? (end - base) : 64;
      int j = 0;
      for (; j + 2 <= m; j += 2){
        const float4 q = *reinterpret_cast<const float4*>(&wsb[wid][j]);
        const float w0 = q.x; const int v0 = __float_as_int(q.y);
        const float w1 = q.z; const int v1 = __float_as_int(q.w);
        const ushort4 h0 = *reinterpret_cast<const ushort4*>(hb + (size_t)v0*256 + fo);
        const ushort4 h1 = *reinterpret_cast<const ushort4*>(hb + (size_t)v1*256 + fo);
        ax += w0*bf2f(h0.x); ay += w0*bf2f(h0.y); az += w0*bf2f(h0.z); aw += w0*bf2f(h0.w);
        bx += w1*bf2f(h1.x); by += w1*bf2f(h1.y); bz += w1*bf2f(h1.z); bw += w1*bf2f(h1.w);
      }
      if (j < m){
        const float2 q = wsb[wid][j];
        const float w0 = q.x; const int v0 = __float_as_int(q.y);
        const ushort4 h0 = *reinterpret_cast<const ushort4*>(hb + (size_t)v0*256 + fo);
        ax += w0*bf2f(h0.x); ay += w0*bf2f(h0.y); az += w0*bf2f(h0.z); aw += w0*bf2f(h0.w);
      }
    }
    float den = den_l;
    #pragma unroll
    for (int o = 32; o; o >>= 1) den += __shfl_xor(den, o, 64);
    const float inv = 1.f/den;
    float4 r;
    r.x = (ax+bx)*inv + bb.x;
    r.y = (ay+by)*inv + bb.y;
    r.z = (az+bz)*inv + bb.z;
    r.w = (aw+bw)*inv + bb.w;
    *reinterpret_cast<float4*>(out + (size_t)node*256 + fo) = r;
    s0 += r.x; s1 += r.y; s2 += r.z; s3 += r.w;
    q0 += r.x*r.x; q1 += r.y*r.y; q2 += r.z*r.z; q3 += r.w*r.w;
  }
  atomicAdd(&sbn[fo+0], s0); atomicAdd(&sbn[fo+1], s1);
  atomicAdd(&sbn[fo+2], s2); atomicAdd(&sbn[fo+3], s3);
  atomicAdd(&sbn[256+fo+0], q0); atomicAdd(&sbn[256+fo+1], q1);
  atomicAdd(&sbn[256+fo+2], q2); atomicAdd(&sbn[256+fo+3], q3);
  __syncthreads();
  atomicAdd(&bnsum[t], sbn[t]);
  atomicAdd(&bnsq[t],  sbn[256+t]);
}

__global__ void k_bnprep(const float* __restrict__ g, const float* __restrict__ be,
                         float* __restrict__ bsum, float* __restrict__ bsq){
  const int f = threadIdx.x;
  const float mean = bsum[f] * (1.0f/N_);
  const float var  = bsq[f]  * (1.0f/N_) - mean*mean;
  const float sc = g[f] / sqrtf(var + EPSV);
  bsum[f] = sc;
  bsq[f]  = be[f] - mean*sc;
}

// ---------------- global mean pool (fused BN2+relu) ----------------
__global__ __launch_bounds__(256) void k_pool(const float* __restrict__ x, const int* __restrict__ batch,
                                              const float* __restrict__ sc, const float* __restrict__ sh,
                                              float* __restrict__ psum, float* __restrict__ pcnt){
  const int f = threadIdx.x;
  const float scf = sc[f], shf = sh[f];
  const int RPB = (N_ + gridDim.x - 1) / gridDim.x;
  const int r0 = blockIdx.x * RPB;
  const int r1 = min(r0 + RPB, N_);
  if (r0 >= N_) return;
  float local = 0.f, c = 0.f;
  int curg = -1;
  for (int r = r0; r < r1; ++r){
    const int g = batch[r];
    if (g != curg){
      if (curg >= 0){
        atomicAdd(&psum[curg*256 + f], local);
        if (f == 0) atomicAdd(&pcnt[curg], c);
      }
      curg = g; local = 0.f; c = 0.f;
    }
    local += fmaxf(x[(size_t)r*256 + f]*scf + shf, 0.f);
    c += 1.f;
  }
  if (curg >= 0){
    atomicAdd(&psum[curg*256 + f], local);
    if (f == 0) atomicAdd(&pcnt[curg], c);
  }
}

// ---------------- FC head ----------------
__global__ __launch_bounds__(256) void k_fc1(const float* __restrict__ psum, const float* __restrict__ pcnt,
                                             const float* __restrict__ w, const float* __restrict__ b,
                                             float* __restrict__ z){
  __shared__ float p[256];
  const int g = blockIdx.x, f = threadIdx.x;
  const float cnt = fmaxf(pcnt[g], 1.f);
  p[f] = psum[g*256 + f] / cnt;
  __syncthreads();
  float acc = b[f];
  #pragma unroll 8
  for (int k = 0; k < 256; ++k) acc += p[k] * w[k*256 + f];
  z[g*256 + f] = fmaxf(acc, 0.f);
}

__global__ __launch_bounds__(128) void k_fc2(const float* __restrict__ zin, const float* __restrict__ w,
                                             const float* __restrict__ b, float* __restrict__ z){
  __shared__ float p[256];
  const int g = blockIdx.x, f = threadIdx.x;
  p[f] = zin[g*256 + f];
  p[f+128] = zin[g*256 + f + 128];
  __syncthreads();
  float acc = b[f];
  #pragma unroll 8
  for (int k = 0; k < 256; ++k) acc += p[k] * w[k*128 + f];
  z[g*128 + f] = fmaxf(acc, 0.f);
}

__global__ __launch_bounds__(64) void k_fc3(const float* __restrict__ zin, const float* __restrict__ w,
                                            const float* __restrict__ b, float* __restrict__ out){
  const int g = threadIdx.x;   // 64 graphs
  float acc = b[0];
  #pragma unroll 8
  for (int k = 0; k < 128; ++k) acc += zin[g*128 + k] * w[k];
  out[g] = acc;
}

// ---------------- launch ----------------
extern "C" void kernel_launch(void* const* d_in, const int* in_sizes, int n_in,
                              void* d_out, int out_size, void* d_ws, size_t ws_size,
                              hipStream_t stream){
  (void)in_sizes; (void)n_in; (void)out_size; (void)ws_size;
  const float* x    = (const float*)d_in[0];
  const float* W1   = (const float*)d_in[1];
  const float* a_s1 = (const float*)d_in[2];
  const float* a_d1 = (const float*)d_in[3];
  const float* b1   = (const float*)d_in[4];
  const float* g1   = (const float*)d_in[5];
  const float* be1  = (const float*)d_in[6];
  const float* W2   = (const float*)d_in[7];
  const float* a_s2 = (const float*)d_in[8];
  const float* a_d2 = (const float*)d_in[9];
  const float* b2   = (const float*)d_in[10];
  const float* g2   = (const float*)d_in[11];
  const float* be2  = (const float*)d_in[12];
  const float* fc1w = (const float*)d_in[13];
  const float* fc1b = (const float*)d_in[14];
  const float* fc2w = (const float*)d_in[15];
  const float* fc2b = (const float*)d_in[16];
  const float* fc3w = (const float*)d_in[17];
  const float* fc3b = (const float*)d_in[18];
  const int*   ei   = (const int*)d_in[19];
  const int*   batch= (const int*)d_in[20];
  float* out = (float*)d_out;

  char* ws = (char*)d_ws;
  size_t off = 0;
  auto alloc = [&](size_t bytes)->char*{
    char* p = ws + off;
    off += (bytes + 255) & ~(size_t)255;
    return p;
  };
  unsigned short* hb = (unsigned short*)alloc((size_t)N_*256*2);
  float* agg    = (float*)alloc((size_t)N_*256*4);
  uint2* staging= (uint2*)alloc((size_t)E_*8);
  int*   col    = (int*)  alloc((size_t)(E_+N_)*4);
  int*   rowp   = (int*)  alloc((size_t)(N_+1)*4);
  int*   deg    = (int*)  alloc((size_t)N_*4);
  int*   cursor = (int*)  alloc((size_t)N_*4);
  int*   bcur   = (int*)  alloc(128*4);
  unsigned short* wt_hi = (unsigned short*)alloc(256*256*2);
  unsigned short* wt_lo = (unsigned short*)alloc(256*256*2);
  float* ssrc   = (float*)alloc((size_t)N_*4);
  float* sdst   = (float*)alloc((size_t)N_*4);
  float* bns1   = (float*)alloc(512*4);
  float* bns2   = (float*)alloc(512*4);
  float* pooled = (float*)alloc((G_*256 + G_)*4);
  float* z1     = (float*)alloc(G_*256*4);
  float* z2     = (float*)alloc(G_*128*4);
  int*   bsums  = (int*)  alloc(1024*4);

  const int NCHUNK = (N_ + 1023) / 1024;   // 98

  // ---- W2 transpose+split (no deps) ----
  k_prepw<<<256, 256, 0, stream>>>(W2, wt_hi, wt_lo);

  // ---- K0: gemm1 part A + degree count ----
  hipMemsetAsync(deg, 0, (size_t)N_*4, stream);
  hipMemsetAsync(ssrc, 0, (size_t)N_*4, stream);
  hipMemsetAsync(sdst, 0, (size_t)N_*4, stream);
  hipMemsetAsync(bns1, 0, 512*4, stream);
  k_g1_count<<<2*G0N + (AUXN - G0N), 256, 0, stream>>>(x, W1, hb, a_s1, a_d1, ssrc, sdst, ei, deg);

  // ---- scans (+ self-loop placement, cursor init, bucket bases) ----
  k_scan1<<<NCHUNK, 1024, 0, stream>>>(deg, rowp, bsums);
  k_scan2<<<1, 128, 0, stream>>>(bsums, NCHUNK);
  k_scan3<<<NCHUNK, 1024, 0, stream>>>(deg, rowp, bsums, cursor, col);
  k_prepb<<<1, 128, 0, stream>>>(rowp, bcur);

  // ---- K1: gemm1 part B + LDS-binned bucket partition ----
  k_g1_pb<<<2*AUXN + (G1N - AUXN), 256, 0, stream>>>(x, W1, hb, a_s1, a_d1, ssrc, sdst, ei, bcur, staging);

  // ---- K2: gemm1 part C + bucket-major fill ----
  k_g1_pc<<<2*AUXN + (G2N - AUXN), 256, 0, stream>>>(x, W1, hb, a_s1, a_d1, ssrc, sdst, staging, cursor, col);

  // ---- layer 1 aggregation (+BN1 stats) ----
  k_agg<<<2048, 256, 0, stream>>>(hb, col, rowp, ssrc, sdst, b1, agg, bns1, bns1 + 256);
  k_bnprep<<<1, 256, 0, stream>>>(g1, be1, bns1, bns1 + 256);

  // ---- layer 2: split-bf16 MFMA GEMM (BN1+relu fused on A-load) ----
  hipMemsetAsync(ssrc, 0, (size_t)N_*4, stream);
  hipMemsetAsync(sdst, 0, (size_t)N_*4, stream);
  hipMemsetAsync(bns2, 0, 512*4, stream);
  k_gemm2_mfma<<<NMT, 256, 0, stream>>>(agg, wt_hi, wt_lo, hb, a_s2, a_d2, ssrc, sdst, bns1, bns1 + 256);
  k_agg<<<2048, 256, 0, stream>>>(hb, col, rowp, ssrc, sdst, b2, agg, bns2, bns2 + 256);
  k_bnprep<<<1, 256, 0, stream>>>(g2, be2, bns2, bns2 + 256);

  // ---- pool (BN2+relu fused) + head ----
  hipMemsetAsync(pooled, 0, (size_t)(G_*256 + G_)*4, stream);
  k_pool<<<512, 256, 0, stream>>>(agg, batch, bns2, bns2 + 256, pooled, pooled + G_*256);
  k_fc1<<<G_, 256, 0, stream>>>(pooled, pooled + G_*256, fc1w, fc1b, z1);
  k_fc2<<<G_, 128, 0, stream>>>(z1, fc2w, fc2b, z2);
  k_fc3<<<1, 64, 0, stream>>>(z2, fc3w, fc3b, out);
}

// Round 10
// 923.010 us; speedup vs baseline: 1.3142x; 1.1736x over previous
//
#include <hip/hip_runtime.h>
#include <hip/hip_bf16.h>

#define N_   100000
#define E_   3200000
#define IN_  128
#define H_   256
#define OUT_ 256
#define G_   64
#define EPSV 1e-5f

#define NMT   1563            // ceil(N/64) M-tiles; 4 col tiles -> 6252 gemm1 blocks
#define EB2   1563            // edges per passB block (2048*1563 >= E)
#define PBBN  2048            // passB aux blocks
#define NBKT  196             // 512-node buckets (196*512 >= N)
#define BSH   9
#define BW_   512
#define SLAB  20480           // slab capacity (mean 16384 + 32 sigma)
#define G1N   3126            // gemm1 ids in K1
#define G2N   3126            // gemm1 ids in K2

typedef short bf8v __attribute__((ext_vector_type(8)));
typedef float f32x4 __attribute__((ext_vector_type(4)));

__device__ __forceinline__ unsigned short f2bf(float x){
  unsigned u = __float_as_uint(x);
  return (unsigned short)((u + 0x7FFFu + ((u >> 16) & 1u)) >> 16);
}
__device__ __forceinline__ float bf2f(unsigned short u){
  return __uint_as_float(((unsigned)u) << 16);
}

// ---------------- slab-count exclusive prefix (196 values, 1 block) ----------------
__global__ void k_bscan(const int* __restrict__ bcnt, int* __restrict__ bpre){
  __shared__ int s[256];
  const int t = threadIdx.x;
  const int v = (t < NBKT) ? bcnt[t] : 0;
  s[t] = v;
  __syncthreads();
  for (int o = 1; o < 256; o <<= 1){
    int x = (t >= o) ? s[t-o] : 0;
    __syncthreads();
    s[t] += x;
    __syncthreads();
  }
  if (t < NBKT) bpre[t] = s[t] - v;
}

// W2 -> transposed split-bf16: Wt_hi/Wt_lo [n][k]
__global__ void k_prepw(const float* __restrict__ W, unsigned short* __restrict__ Wt_hi,
                        unsigned short* __restrict__ Wt_lo){
  const int k = blockIdx.x, n = threadIdx.x;
  const float v = W[k*256 + n];
  const unsigned short h = f2bf(v);
  const float r = v - bf2f(h);
  Wt_hi[n*256 + k] = h;
  Wt_lo[n*256 + k] = f2bf(r);
}

// ---------------- shared fp32 GEMM tile body (gemm1 / cover role) ----------------
template<int K, bool BNIN>
__device__ __forceinline__ void gemm_tile(float (*As)[68], float (*Ws)[68],
                                          const float* __restrict__ A, const float* __restrict__ W,
                                          unsigned short* __restrict__ hb, int nrows,
                                          const float* __restrict__ a_s, const float* __restrict__ a_d,
                                          float* __restrict__ ssrc, float* __restrict__ sdst,
                                          const float* __restrict__ bnsc, const float* __restrict__ bnsh,
                                          int bx, int by, int t){
  const int bm = bx * 64;
  const int bn = by * 64;
  const int lm = t >> 2,  lk = (t & 3) * 4;
  const int wk = t >> 4,  wn = (t & 15) * 4;
  const int tm = (t >> 4) * 4, tn = (t & 15) * 4;
  float acc[4][4];
  #pragma unroll
  for (int i=0;i<4;i++){
    #pragma unroll
    for (int j=0;j<4;j++) acc[i][j]=0.f;
  }
  for (int kb = 0; kb < K; kb += 16){
    const int arow = bm + lm;
    float4 av = make_float4(0.f,0.f,0.f,0.f);
    if (arow < nrows){
      av = *reinterpret_cast<const float4*>(A + (size_t)arow*K + kb + lk);
      if (BNIN){
        const float4 sc = *reinterpret_cast<const float4*>(bnsc + kb + lk);
        const float4 sh = *reinterpret_cast<const float4*>(bnsh + kb + lk);
        av.x = fmaxf(av.x*sc.x + sh.x, 0.f);
        av.y = fmaxf(av.y*sc.y + sh.y, 0.f);
        av.z = fmaxf(av.z*sc.z + sh.z, 0.f);
        av.w = fmaxf(av.w*sc.w + sh.w, 0.f);
      }
    }
    const float4 wv = *reinterpret_cast<const float4*>(W + (size_t)(kb + wk)*256 + bn + wn);
    __syncthreads();
    As[lk+0][lm]=av.x; As[lk+1][lm]=av.y; As[lk+2][lm]=av.z; As[lk+3][lm]=av.w;
    *reinterpret_cast<float4*>(&Ws[wk][wn]) = wv;
    __syncthreads();
    #pragma unroll
    for (int k=0;k<16;k++){
      const float4 a  = *reinterpret_cast<const float4*>(&As[k][tm]);
      const float4 bv = *reinterpret_cast<const float4*>(&Ws[k][tn]);
      acc[0][0]+=a.x*bv.x; acc[0][1]+=a.x*bv.y; acc[0][2]+=a.x*bv.z; acc[0][3]+=a.x*bv.w;
      acc[1][0]+=a.y*bv.x; acc[1][1]+=a.y*bv.y; acc[1][2]+=a.y*bv.z; acc[1][3]+=a.y*bv.w;
      acc[2][0]+=a.z*bv.x; acc[2][1]+=a.z*bv.y; acc[2][2]+=a.z*bv.z; acc[2][3]+=a.z*bv.w;
      acc[3][0]+=a.w*bv.x; acc[3][1]+=a.w*bv.y; acc[3][2]+=a.w*bv.z; acc[3][3]+=a.w*bv.w;
    }
  }
  #pragma unroll
  for (int i=0;i<4;i++){
    const int row = bm + tm + i;
    if (row < nrows){
      ushort4 o;
      o.x = f2bf(acc[i][0]); o.y = f2bf(acc[i][1]);
      o.z = f2bf(acc[i][2]); o.w = f2bf(acc[i][3]);
      *reinterpret_cast<ushort4*>(hb + (size_t)row*256 + bn + tn) = o;
    }
  }
  const float4 asv = *reinterpret_cast<const float4*>(a_s + bn + tn);
  const float4 adv = *reinterpret_cast<const float4*>(a_d + bn + tn);
  #pragma unroll
  for (int i=0;i<4;i++){
    float ps = acc[i][0]*asv.x + acc[i][1]*asv.y + acc[i][2]*asv.z + acc[i][3]*asv.w;
    float pd = acc[i][0]*adv.x + acc[i][1]*adv.y + acc[i][2]*adv.z + acc[i][3]*adv.w;
    #pragma unroll
    for (int o=1;o<16;o<<=1){ ps += __shfl_xor(ps, o, 64); pd += __shfl_xor(pd, o, 64); }
    if ((t & 15) == 0){
      const int row = bm + tm + i;
      if (row < nrows){ atomicAdd(&ssrc[row], ps); atomicAdd(&sdst[row], pd); }
    }
  }
}

__device__ __forceinline__ void split_ids2(int bid, int GN, int auxn, int& g, int& aux){
  g = -1; aux = -1;
  const int nmin = (GN < auxn) ? GN : auxn;
  if (bid < 2*nmin){ if (bid & 1) aux = bid >> 1; else g = bid >> 1; }
  else {
    int r = bid - 2*nmin;
    if (GN > auxn) g = nmin + r; else aux = nmin + r;
  }
}

// ---------------- K1: gemm1 part A + passB slab partition ----------------
__global__ __launch_bounds__(256) void k_g1_pb(const float* __restrict__ A, const float* __restrict__ W,
                                               unsigned short* __restrict__ hb,
                                               const float* __restrict__ a_s, const float* __restrict__ a_d,
                                               float* __restrict__ ssrc, float* __restrict__ sdst,
                                               const int* __restrict__ ei, int* __restrict__ bcnt,
                                               uint2* __restrict__ staging){
  __shared__ __align__(16) char um[14856];   // union: gemm tiles (8704) | passB structures
  const int t = threadIdx.x;
  int g, aux;
  split_ids2(blockIdx.x, G1N, PBBN, g, aux);
  if (g >= 0){
    float (*As)[68] = reinterpret_cast<float(*)[68]>(um);
    float (*Ws)[68] = reinterpret_cast<float(*)[68]>(um + 4352);
    gemm_tile<IN_,false>(As, Ws, A, W, hb, N_, a_s, a_d, ssrc, sdst, nullptr, nullptr,
                         g % NMT, g / NMT, t);
    return;
  }
  uint2* slots = reinterpret_cast<uint2*>(um);          // 1563*8 = 12504
  int* hist  = reinterpret_cast<int*>(um + 12504);      // 196
  int* lbase = reinterpret_cast<int*>(um + 13288);      // 196
  int* cur2  = reinterpret_cast<int*>(um + 14072);      // 196
  const int e0 = aux*EB2;
  const int e1 = min(e0 + EB2, E_);
  if (t < NBKT) hist[t] = 0;
  __syncthreads();
  for (int e = e0 + t; e < e1; e += 256)
    atomicAdd(&hist[((unsigned)ei[E_ + e]) >> BSH], 1);
  __syncthreads();
  if (t < NBKT) lbase[t] = hist[t];
  __syncthreads();
  for (int o = 1; o < NBKT; o <<= 1){
    int x = (t >= o && t < NBKT) ? lbase[t-o] : 0;
    __syncthreads();
    if (t < NBKT) lbase[t] += x;
    __syncthreads();
  }
  int excl = 0;
  if (t < NBKT) excl = lbase[t] - hist[t];
  __syncthreads();
  if (t < NBKT){ lbase[t] = excl; cur2[t] = excl; }
  __syncthreads();
  for (int e = e0 + t; e < e1; e += 256){
    const int s = ei[e], d = ei[E_ + e];
    const int b = ((unsigned)d) >> BSH;
    const int slot = atomicAdd(&cur2[b], 1);
    slots[slot] = make_uint2((unsigned)s, (unsigned)d);
  }
  __syncthreads();
  if (t < NBKT){
    const int c = cur2[t] - lbase[t];
    hist[t] = (c > 0) ? atomicAdd(&bcnt[t], c) : 0;    // hist := base within slab
  }
  __syncthreads();
  const int total = e1 - e0;
  for (int i = t; i < total; i += 256){
    const uint2 u = slots[i];
    const int b = u.y >> BSH;
    staging[(size_t)b*SLAB + hist[b] + (i - lbase[b])] = u;   // coalesced runs
  }
}

// ---------------- K2: gemm1 part B + passC per-bucket counting sort ----------------
// Builds rowp (coalesced) + col (self-loops + edges) with LDS cursors; col writes land
// in a ~66KB L2-hot window per bucket.
__global__ __launch_bounds__(256) void k_g1_pc(const float* __restrict__ A, const float* __restrict__ W,
                                               unsigned short* __restrict__ hb,
                                               const float* __restrict__ a_s, const float* __restrict__ a_d,
                                               float* __restrict__ ssrc, float* __restrict__ sdst,
                                               const uint2* __restrict__ staging, const int* __restrict__ bcnt,
                                               const int* __restrict__ bpre, int* __restrict__ rowp,
                                               int* __restrict__ col){
  __shared__ __align__(16) char um[8704];   // union: gemm tiles | passC (h2[512]+cur[512]=4096)
  const int t = threadIdx.x;
  int g, aux;
  split_ids2(blockIdx.x, G2N, NBKT, g, aux);
  if (g >= 0){
    float (*As)[68] = reinterpret_cast<float(*)[68]>(um);
    float (*Ws)[68] = reinterpret_cast<float(*)[68]>(um + 4352);
    const int gg = G1N + g;
    gemm_tile<IN_,false>(As, Ws, A, W, hb, N_, a_s, a_d, ssrc, sdst, nullptr, nullptr,
                         gg % NMT, gg / NMT, t);
    return;
  }
  int* h2  = reinterpret_cast<int*>(um);          // [512] degree counts
  int* cur = reinterpret_cast<int*>(um + 2048);   // [512] global col cursors
  const int b   = aux;
  const int lo  = b << BSH;
  const int hi  = min(lo + BW_, N_);
  const int nn  = hi - lo;
  const int cb  = bcnt[b];
  const int pre = bpre[b];
  const uint2* slab = staging + (size_t)b*SLAB;
  h2[t] = 0; h2[t+256] = 0;
  __syncthreads();
  // pass 1: per-node degree histogram
  for (int i = t; i < cb; i += 256)
    atomicAdd(&h2[(int)slab[i].y - lo], 1);
  __syncthreads();
  const int a0 = h2[t], a1 = h2[t+256];
  // inclusive scan over 512 entries (2 per thread)
  for (int o = 1; o < 512; o <<= 1){
    const int x0 = (t >= o) ? h2[t-o] : 0;
    const int x1 = (t+256 >= o) ? h2[t+256-o] : 0;
    __syncthreads();
    h2[t] += x0; h2[t+256] += x1;
    __syncthreads();
  }
  // rowp + self-loop + cursor init  (rowp[i] = pre + lo + j + exclusive_scan)
  if (t < nn){
    const int rp = pre + lo + t + (h2[t] - a0);
    rowp[lo + t] = rp;
    col[rp] = lo + t;
    cur[t] = rp + 1;
  }
  const int j1 = t + 256;
  if (j1 < nn){
    const int rp = pre + lo + j1 + (h2[j1] - a1);
    rowp[lo + j1] = rp;
    col[rp] = lo + j1;
    cur[j1] = rp + 1;
  }
  if (b == NBKT-1 && t == 0) rowp[N_] = E_ + N_;
  __syncthreads();
  // pass 2: scatter edges via LDS cursors
  for (int i = t; i < cb; i += 256){
    const uint2 u = slab[i];
    const int pos = atomicAdd(&cur[(int)u.y - lo], 1);
    col[pos] = (int)u.x;
  }
}

// ---------------- gemm2: split-bf16 MFMA (D = A·W2, BN1+relu fused on A) ----------------
__global__ __launch_bounds__(256) void k_gemm2_mfma(const float* __restrict__ A,
                                                    const unsigned short* __restrict__ Wt_hi,
                                                    const unsigned short* __restrict__ Wt_lo,
                                                    unsigned short* __restrict__ hb,
                                                    const float* __restrict__ a_s, const float* __restrict__ a_d,
                                                    float* __restrict__ ssrc, float* __restrict__ sdst,
                                                    const float* __restrict__ bnsc, const float* __restrict__ bnsh){
  __shared__ short As_hi[64][40];
  __shared__ short As_lo[64][40];
  const int t = threadIdx.x;
  const int lane = t & 63;
  const int w = t >> 6;
  const int l15 = lane & 15;
  const int lk  = lane >> 4;
  const int m0 = blockIdx.x * 64;
  const int srow = t >> 2;
  const int skq  = (t & 3) * 8;
  f32x4 acc[4][4];
  #pragma unroll
  for (int fm=0; fm<4; fm++)
    #pragma unroll
    for (int fn=0; fn<4; fn++) acc[fm][fn] = (f32x4)0.f;
  float4 asv[4], adv[4];
  #pragma unroll
  for (int fn=0; fn<4; fn++){
    asv[fn] = *reinterpret_cast<const float4*>(a_s + w*64 + fn*16 + lk*4);
    adv[fn] = *reinterpret_cast<const float4*>(a_d + w*64 + fn*16 + lk*4);
  }
  const int arow = m0 + srow;
  for (int kb = 0; kb < 256; kb += 32){
    float v[8];
    if (arow < N_){
      const float4 x0 = *reinterpret_cast<const float4*>(A + (size_t)arow*256 + kb + skq);
      const float4 x1 = *reinterpret_cast<const float4*>(A + (size_t)arow*256 + kb + skq + 4);
      const float4 s0 = *reinterpret_cast<const float4*>(bnsc + kb + skq);
      const float4 s1 = *reinterpret_cast<const float4*>(bnsc + kb + skq + 4);
      const float4 h0 = *reinterpret_cast<const float4*>(bnsh + kb + skq);
      const float4 h1 = *reinterpret_cast<const float4*>(bnsh + kb + skq + 4);
      v[0]=fmaxf(x0.x*s0.x+h0.x,0.f); v[1]=fmaxf(x0.y*s0.y+h0.y,0.f);
      v[2]=fmaxf(x0.z*s0.z+h0.z,0.f); v[3]=fmaxf(x0.w*s0.w+h0.w,0.f);
      v[4]=fmaxf(x1.x*s1.x+h1.x,0.f); v[5]=fmaxf(x1.y*s1.y+h1.y,0.f);
      v[6]=fmaxf(x1.z*s1.z+h1.z,0.f); v[7]=fmaxf(x1.w*s1.w+h1.w,0.f);
    } else {
      #pragma unroll
      for (int j=0;j<8;j++) v[j]=0.f;
    }
    unsigned hh[4], ll[4];
    #pragma unroll
    for (int j=0;j<4;j++){
      const unsigned short ha = f2bf(v[2*j]),   hb_ = f2bf(v[2*j+1]);
      const unsigned short la = f2bf(v[2*j]   - bf2f(ha));
      const unsigned short lb = f2bf(v[2*j+1] - bf2f(hb_));
      hh[j] = (unsigned)ha | ((unsigned)hb_ << 16);
      ll[j] = (unsigned)la | ((unsigned)lb << 16);
    }
    __syncthreads();
    *reinterpret_cast<uint4*>(&As_hi[srow][skq]) = make_uint4(hh[0],hh[1],hh[2],hh[3]);
    *reinterpret_cast<uint4*>(&As_lo[srow][skq]) = make_uint4(ll[0],ll[1],ll[2],ll[3]);
    __syncthreads();
    bf8v afh[4], afl[4];
    #pragma unroll
    for (int fn=0; fn<4; fn++){
      const size_t nrow = (size_t)(w*64 + fn*16 + l15);
      afh[fn] = *reinterpret_cast<const bf8v*>(Wt_hi + nrow*256 + kb + lk*8);
      afl[fn] = *reinterpret_cast<const bf8v*>(Wt_lo + nrow*256 + kb + lk*8);
    }
    #pragma unroll
    for (int fm=0; fm<4; fm++){
      const bf8v bh = *reinterpret_cast<const bf8v*>(&As_hi[fm*16 + l15][lk*8]);
      const bf8v bl = *reinterpret_cast<const bf8v*>(&As_lo[fm*16 + l15][lk*8]);
      #pragma unroll
      for (int fn=0; fn<4; fn++){
        acc[fm][fn] = __builtin_amdgcn_mfma_f32_16x16x32_bf16(afh[fn], bh, acc[fm][fn], 0,0,0);
        acc[fm][fn] = __builtin_amdgcn_mfma_f32_16x16x32_bf16(afl[fn], bh, acc[fm][fn], 0,0,0);
        acc[fm][fn] = __builtin_amdgcn_mfma_f32_16x16x32_bf16(afh[fn], bl, acc[fm][fn], 0,0,0);
      }
    }
  }
  #pragma unroll
  for (int fm=0; fm<4; fm++){
    const int m = m0 + fm*16 + l15;
    float ps = 0.f, pd = 0.f;
    #pragma unroll
    for (int fn=0; fn<4; fn++){
      const f32x4 c = acc[fm][fn];
      ps += c[0]*asv[fn].x + c[1]*asv[fn].y + c[2]*asv[fn].z + c[3]*asv[fn].w;
      pd += c[0]*adv[fn].x + c[1]*adv[fn].y + c[2]*adv[fn].z + c[3]*adv[fn].w;
      if (m < N_){
        ushort4 o;
        o.x = f2bf(c[0]); o.y = f2bf(c[1]); o.z = f2bf(c[2]); o.w = f2bf(c[3]);
        *reinterpret_cast<ushort4*>(hb + (size_t)m*256 + w*64 + fn*16 + lk*4) = o;
      }
    }
    ps += __shfl_xor(ps, 16, 64); ps += __shfl_xor(ps, 32, 64);
    pd += __shfl_xor(pd, 16, 64); pd += __shfl_xor(pd, 32, 64);
    if (lk == 0 && m < N_){
      atomicAdd(&ssrc[m], ps);
      atomicAdd(&sdst[m], pd);
    }
  }
}

// ---------------- GAT aggregation (R5-proven) + fused BN stats ----------------
__global__ __launch_bounds__(256) void k_agg(const unsigned short* __restrict__ hb, const int* __restrict__ col,
                                             const int* __restrict__ rowp, const float* __restrict__ ssrc,
                                             const float* __restrict__ sdst, const float* __restrict__ bias,
                                             float* __restrict__ out, float* __restrict__ bnsum,
                                             float* __restrict__ bnsq){
  __shared__ float sbn[512];
  __shared__ __align__(16) float2 wsb[4][64];
  const int t = threadIdx.x;
  sbn[t] = 0.f; sbn[t+256] = 0.f;
  const int lane = t & 63;
  const int wid  = t >> 6;
  const int fo = lane*4;
  const float4 bb = *reinterpret_cast<const float4*>(bias + fo);
  float s0=0.f,s1=0.f,s2=0.f,s3=0.f, q0=0.f,q1=0.f,q2=0.f,q3=0.f;
  __syncthreads();
  for (int node = blockIdx.x*4 + wid; node < N_; node += gridDim.x*4){
    const int start = rowp[node];
    const int end   = rowp[node+1];
    const float sd  = sdst[node];
    float den_l = 0.f;
    float ax=0.f, ay=0.f, az=0.f, aw=0.f;
    float bx=0.f, by=0.f, bz=0.f, bw=0.f;
    for (int base = start; base < end; base += 64){
      const int p = base + lane;
      float w = 0.f; int s = 0;
      if (p < end){
        s = col[p];
        float e = ssrc[s] + sd;
        e = e > 0.f ? e : 0.2f*e;
        w = expf(e);
      }
      den_l += w;
      wsb[wid][lane] = make_float2(w, __int_as_float(s));
      const int m = (end - base < 64) ? (end - base) : 64;
      int j = 0;
      for (; j + 2 <= m; j += 2){
        const float4 q = *reinterpret_cast<const float4*>(&wsb[wid][j]);
        const float w0 = q.x; const int v0 = __float_as_int(q.y);
        const float w1 = q.z; const int v1 = __float_as_int(q.w);
        const ushort4 h0 = *reinterpret_cast<const ushort4*>(hb + (size_t)v0*256 + fo);
        const ushort4 h1 = *reinterpret_cast<const ushort4*>(hb + (size_t)v1*256 + fo);
        ax += w0*bf2f(h0.x); ay += w0*bf2f(h0.y); az += w0*bf2f(h0.z); aw += w0*bf2f(h0.w);
        bx += w1*bf2f(h1.x); by += w1*bf2f(h1.y); bz += w1*bf2f(h1.z); bw += w1*bf2f(h1.w);
      }
      if (j < m){
        const float2 q = wsb[wid][j];
        const float w0 = q.x; const int v0 = __float_as_int(q.y);
        const ushort4 h0 = *reinterpret_cast<const ushort4*>(hb + (size_t)v0*256 + fo);
        ax += w0*bf2f(h0.x); ay += w0*bf2f(h0.y); az += w0*bf2f(h0.z); aw += w0*bf2f(h0.w);
      }
    }
    float den = den_l;
    #pragma unroll
    for (int o = 32; o; o >>= 1) den += __shfl_xor(den, o, 64);
    const float inv = 1.f/den;
    float4 r;
    r.x = (ax+bx)*inv + bb.x;
    r.y = (ay+by)*inv + bb.y;
    r.z = (az+bz)*inv + bb.z;
    r.w = (aw+bw)*inv + bb.w;
    *reinterpret_cast<float4*>(out + (size_t)node*256 + fo) = r;
    s0 += r.x; s1 += r.y; s2 += r.z; s3 += r.w;
    q0 += r.x*r.x; q1 += r.y*r.y; q2 += r.z*r.z; q3 += r.w*r.w;
  }
  atomicAdd(&sbn[fo+0], s0); atomicAdd(&sbn[fo+1], s1);
  atomicAdd(&sbn[fo+2], s2); atomicAdd(&sbn[fo+3], s3);
  atomicAdd(&sbn[256+fo+0], q0); atomicAdd(&sbn[256+fo+1], q1);
  atomicAdd(&sbn[256+fo+2], q2); atomicAdd(&sbn[256+fo+3], q3);
  __syncthreads();
  atomicAdd(&bnsum[t], sbn[t]);
  atomicAdd(&bnsq[t],  sbn[256+t]);
}

__global__ void k_bnprep(const float* __restrict__ g, const float* __restrict__ be,
                         float* __restrict__ bsum, float* __restrict__ bsq){
  const int f = threadIdx.x;
  const float mean = bsum[f] * (1.0f/N_);
  const float var  = bsq[f]  * (1.0f/N_) - mean*mean;
  const float sc = g[f] / sqrtf(var + EPSV);
  bsum[f] = sc;
  bsq[f]  = be[f] - mean*sc;
}

// ---------------- global mean pool (fused BN2+relu) ----------------
__global__ __launch_bounds__(256) void k_pool(const float* __restrict__ x, const int* __restrict__ batch,
                                              const float* __restrict__ sc, const float* __restrict__ sh,
                                              float* __restrict__ psum, float* __restrict__ pcnt){
  const int f = threadIdx.x;
  const float scf = sc[f], shf = sh[f];
  const int RPB = (N_ + gridDim.x - 1) / gridDim.x;
  const int r0 = blockIdx.x * RPB;
  const int r1 = min(r0 + RPB, N_);
  if (r0 >= N_) return;
  float local = 0.f, c = 0.f;
  int curg = -1;
  for (int r = r0; r < r1; ++r){
    const int g = batch[r];
    if (g != curg){
      if (curg >= 0){
        atomicAdd(&psum[curg*256 + f], local);
        if (f == 0) atomicAdd(&pcnt[curg], c);
      }
      curg = g; local = 0.f; c = 0.f;
    }
    local += fmaxf(x[(size_t)r*256 + f]*scf + shf, 0.f);
    c += 1.f;
  }
  if (curg >= 0){
    atomicAdd(&psum[curg*256 + f], local);
    if (f == 0) atomicAdd(&pcnt[curg], c);
  }
}

// ---------------- FC head ----------------
__global__ __launch_bounds__(256) void k_fc1(const float* __restrict__ psum, const float* __restrict__ pcnt,
                                             const float* __restrict__ w, const float* __restrict__ b,
                                             float* __restrict__ z){
  __shared__ float p[256];
  const int g = blockIdx.x, f = threadIdx.x;
  const float cnt = fmaxf(pcnt[g], 1.f);
  p[f] = psum[g*256 + f] / cnt;
  __syncthreads();
  float acc = b[f];
  #pragma unroll 8
  for (int k = 0; k < 256; ++k) acc += p[k] * w[k*256 + f];
  z[g*256 + f] = fmaxf(acc, 0.f);
}

__global__ __launch_bounds__(128) void k_fc2(const float* __restrict__ zin, const float* __restrict__ w,
                                             const float* __restrict__ b, float* __restrict__ z){
  __shared__ float p[256];
  const int g = blockIdx.x, f = threadIdx.x;
  p[f] = zin[g*256 + f];
  p[f+128] = zin[g*256 + f + 128];
  __syncthreads();
  float acc = b[f];
  #pragma unroll 8
  for (int k = 0; k < 256; ++k) acc += p[k] * w[k*128 + f];
  z[g*128 + f] = fmaxf(acc, 0.f);
}

__global__ __launch_bounds__(64) void k_fc3(const float* __restrict__ zin, const float* __restrict__ w,
                                            const float* __restrict__ b, float* __restrict__ out){
  const int g = threadIdx.x;   // 64 graphs
  float acc = b[0];
  #pragma unroll 8
  for (int k = 0; k < 128; ++k) acc += zin[g*128 + k] * w[k];
  out[g] = acc;
}

// ---------------- launch ----------------
extern "C" void kernel_launch(void* const* d_in, const int* in_sizes, int n_in,
                              void* d_out, int out_size, void* d_ws, size_t ws_size,
                              hipStream_t stream){
  (void)in_sizes; (void)n_in; (void)out_size; (void)ws_size;
  const float* x    = (const float*)d_in[0];
  const float* W1   = (const float*)d_in[1];
  const float* a_s1 = (const float*)d_in[2];
  const float* a_d1 = (const float*)d_in[3];
  const float* b1   = (const float*)d_in[4];
  const float* g1   = (const float*)d_in[5];
  const float* be1  = (const float*)d_in[6];
  const float* W2   = (const float*)d_in[7];
  const float* a_s2 = (const float*)d_in[8];
  const float* a_d2 = (const float*)d_in[9];
  const float* b2   = (const float*)d_in[10];
  const float* g2   = (const float*)d_in[11];
  const float* be2  = (const float*)d_in[12];
  const float* fc1w = (const float*)d_in[13];
  const float* fc1b = (const float*)d_in[14];
  const float* fc2w = (const float*)d_in[15];
  const float* fc2b = (const float*)d_in[16];
  const float* fc3w = (const float*)d_in[17];
  const float* fc3b = (const float*)d_in[18];
  const int*   ei   = (const int*)d_in[19];
  const int*   batch= (const int*)d_in[20];
  float* out = (float*)d_out;

  char* ws = (char*)d_ws;
  size_t off = 0;
  auto alloc = [&](size_t bytes)->char*{
    char* p = ws + off;
    off += (bytes + 255) & ~(size_t)255;
    return p;
  };
  unsigned short* hb = (unsigned short*)alloc((size_t)N_*256*2);
  float* agg    = (float*)alloc((size_t)N_*256*4);
  uint2* staging= (uint2*)alloc((size_t)NBKT*SLAB*8);   // 32.1 MB slabs
  int*   col    = (int*)  alloc((size_t)(E_+N_)*4);
  int*   rowp   = (int*)  alloc((size_t)(N_+1)*4);
  int*   bcnt   = (int*)  alloc(NBKT*4);
  int*   bpre   = (int*)  alloc(NBKT*4);
  unsigned short* wt_hi = (unsigned short*)alloc(256*256*2);
  unsigned short* wt_lo = (unsigned short*)alloc(256*256*2);
  float* ssrc   = (float*)alloc((size_t)N_*4);
  float* sdst   = (float*)alloc((size_t)N_*4);
  float* bns1   = (float*)alloc(512*4);
  float* bns2   = (float*)alloc(512*4);
  float* pooled = (float*)alloc((G_*256 + G_)*4);
  float* z1     = (float*)alloc(G_*256*4);
  float* z2     = (float*)alloc(G_*128*4);

  // ---- W2 transpose+split (no deps) ----
  k_prepw<<<256, 256, 0, stream>>>(W2, wt_hi, wt_lo);

  // ---- K1: gemm1 part A + slab partition ----
  hipMemsetAsync(bcnt, 0, NBKT*4, stream);
  hipMemsetAsync(ssrc, 0, (size_t)N_*4, stream);
  hipMemsetAsync(sdst, 0, (size_t)N_*4, stream);
  hipMemsetAsync(bns1, 0, 512*4, stream);
  k_g1_pb<<<G1N + PBBN, 256, 0, stream>>>(x, W1, hb, a_s1, a_d1, ssrc, sdst, ei, bcnt, staging);

  // ---- slab prefix ----
  k_bscan<<<1, 256, 0, stream>>>(bcnt, bpre);

  // ---- K2: gemm1 part B + per-bucket counting sort (rowp + col) ----
  k_g1_pc<<<G2N + NBKT, 256, 0, stream>>>(x, W1, hb, a_s1, a_d1, ssrc, sdst, staging, bcnt, bpre, rowp, col);

  // ---- layer 1 aggregation (+BN1 stats) ----
  k_agg<<<2048, 256, 0, stream>>>(hb, col, rowp, ssrc, sdst, b1, agg, bns1, bns1 + 256);
  k_bnprep<<<1, 256, 0, stream>>>(g1, be1, bns1, bns1 + 256);

  // ---- layer 2: split-bf16 MFMA GEMM (BN1+relu fused on A-load) ----
  hipMemsetAsync(ssrc, 0, (size_t)N_*4, stream);
  hipMemsetAsync(sdst, 0, (size_t)N_*4, stream);
  hipMemsetAsync(bns2, 0, 512*4, stream);
  k_gemm2_mfma<<<NMT, 256, 0, stream>>>(agg, wt_hi, wt_lo, hb, a_s2, a_d2, ssrc, sdst, bns1, bns1 + 256);
  k_agg<<<2048, 256, 0, stream>>>(hb, col, rowp, ssrc, sdst, b2, agg, bns2, bns2 + 256);
  k_bnprep<<<1, 256, 0, stream>>>(g2, be2, bns2, bns2 + 256);

  // ---- pool (BN2+relu fused) + head ----
  hipMemsetAsync(pooled, 0, (size_t)(G_*256 + G_)*4, stream);
  k_pool<<<512, 256, 0, stream>>>(agg, batch, bns2, bns2 + 256, pooled, pooled + G_*256);
  k_fc1<<<G_, 256, 0, stream>>>(pooled, pooled + G_*256, fc1w, fc1b, z1);
  k_fc2<<<G_, 128, 0, stream>>>(z1, fc2w, fc2b, z2);
  k_fc3<<<1, 64, 0, stream>>>(z2, fc3w, fc3b, out);
}

// Round 11
// 874.749 us; speedup vs baseline: 1.3868x; 1.0552x over previous
//
#include <hip/hip_runtime.h>
#include <hip/hip_bf16.h>

#define N_   100000
#define E_   3200000
#define IN_  128
#define H_   256
#define OUT_ 256
#define G_   64
#define EPSV 1e-5f

#define NMT   1563            // ceil(N/64) M-tiles; 4 col tiles -> 6252 gemm1 blocks
#define EB2   1563            // edges per passB block (2048*1563 >= E)
#define PBBN  2048            // passB aux blocks
#define NBKT  196             // 512-node buckets (196*512 >= N)
#define BSH   9
#define BW_   512
#define SLAB  20480           // slab capacity (mean 16384 + 32 sigma)
#define G1N   3126            // gemm1 ids in K1
#define G2N   3126            // gemm1 ids in K2

typedef short bf8v __attribute__((ext_vector_type(8)));
typedef float f32x4 __attribute__((ext_vector_type(4)));

__device__ __forceinline__ unsigned short f2bf(float x){
  unsigned u = __float_as_uint(x);
  return (unsigned short)((u + 0x7FFFu + ((u >> 16) & 1u)) >> 16);
}
__device__ __forceinline__ float bf2f(unsigned short u){
  return __uint_as_float(((unsigned)u) << 16);
}
__device__ __forceinline__ float bflo(unsigned v){ return __uint_as_float(v << 16); }
__device__ __forceinline__ float bfhi(unsigned v){ return __uint_as_float(v & 0xffff0000u); }

// ---------------- slab-count exclusive prefix (196 values, 1 block) ----------------
__global__ void k_bscan(const int* __restrict__ bcnt, int* __restrict__ bpre){
  __shared__ int s[256];
  const int t = threadIdx.x;
  const int v = (t < NBKT) ? bcnt[t] : 0;
  s[t] = v;
  __syncthreads();
  for (int o = 1; o < 256; o <<= 1){
    int x = (t >= o) ? s[t-o] : 0;
    __syncthreads();
    s[t] += x;
    __syncthreads();
  }
  if (t < NBKT) bpre[t] = s[t] - v;
}

// W2 -> transposed split-bf16: Wt_hi/Wt_lo [n][k]
__global__ void k_prepw(const float* __restrict__ W, unsigned short* __restrict__ Wt_hi,
                        unsigned short* __restrict__ Wt_lo){
  const int k = blockIdx.x, n = threadIdx.x;
  const float v = W[k*256 + n];
  const unsigned short h = f2bf(v);
  const float r = v - bf2f(h);
  Wt_hi[n*256 + k] = h;
  Wt_lo[n*256 + k] = f2bf(r);
}

// ---------------- shared fp32 GEMM tile body (gemm1 / cover role) ----------------
template<int K>
__device__ __forceinline__ void gemm_tile(float (*As)[68], float (*Ws)[68],
                                          const float* __restrict__ A, const float* __restrict__ W,
                                          unsigned short* __restrict__ hb, int nrows,
                                          const float* __restrict__ a_s, const float* __restrict__ a_d,
                                          float* __restrict__ ssrc, float* __restrict__ sdst,
                                          int bx, int by, int t){
  const int bm = bx * 64;
  const int bn = by * 64;
  const int lm = t >> 2,  lk = (t & 3) * 4;
  const int wk = t >> 4,  wn = (t & 15) * 4;
  const int tm = (t >> 4) * 4, tn = (t & 15) * 4;
  float acc[4][4];
  #pragma unroll
  for (int i=0;i<4;i++){
    #pragma unroll
    for (int j=0;j<4;j++) acc[i][j]=0.f;
  }
  for (int kb = 0; kb < K; kb += 16){
    const int arow = bm + lm;
    float4 av = make_float4(0.f,0.f,0.f,0.f);
    if (arow < nrows){
      av = *reinterpret_cast<const float4*>(A + (size_t)arow*K + kb + lk);
    }
    const float4 wv = *reinterpret_cast<const float4*>(W + (size_t)(kb + wk)*256 + bn + wn);
    __syncthreads();
    As[lk+0][lm]=av.x; As[lk+1][lm]=av.y; As[lk+2][lm]=av.z; As[lk+3][lm]=av.w;
    *reinterpret_cast<float4*>(&Ws[wk][wn]) = wv;
    __syncthreads();
    #pragma unroll
    for (int k=0;k<16;k++){
      const float4 a  = *reinterpret_cast<const float4*>(&As[k][tm]);
      const float4 bv = *reinterpret_cast<const float4*>(&Ws[k][tn]);
      acc[0][0]+=a.x*bv.x; acc[0][1]+=a.x*bv.y; acc[0][2]+=a.x*bv.z; acc[0][3]+=a.x*bv.w;
      acc[1][0]+=a.y*bv.x; acc[1][1]+=a.y*bv.y; acc[1][2]+=a.y*bv.z; acc[1][3]+=a.y*bv.w;
      acc[2][0]+=a.z*bv.x; acc[2][1]+=a.z*bv.y; acc[2][2]+=a.z*bv.z; acc[2][3]+=a.z*bv.w;
      acc[3][0]+=a.w*bv.x; acc[3][1]+=a.w*bv.y; acc[3][2]+=a.w*bv.z; acc[3][3]+=a.w*bv.w;
    }
  }
  #pragma unroll
  for (int i=0;i<4;i++){
    const int row = bm + tm + i;
    if (row < nrows){
      ushort4 o;
      o.x = f2bf(acc[i][0]); o.y = f2bf(acc[i][1]);
      o.z = f2bf(acc[i][2]); o.w = f2bf(acc[i][3]);
      *reinterpret_cast<ushort4*>(hb + (size_t)row*256 + bn + tn) = o;
    }
  }
  const float4 asv = *reinterpret_cast<const float4*>(a_s + bn + tn);
  const float4 adv = *reinterpret_cast<const float4*>(a_d + bn + tn);
  #pragma unroll
  for (int i=0;i<4;i++){
    float ps = acc[i][0]*asv.x + acc[i][1]*asv.y + acc[i][2]*asv.z + acc[i][3]*asv.w;
    float pd = acc[i][0]*adv.x + acc[i][1]*adv.y + acc[i][2]*adv.z + acc[i][3]*adv.w;
    #pragma unroll
    for (int o=1;o<16;o<<=1){ ps += __shfl_xor(ps, o, 64); pd += __shfl_xor(pd, o, 64); }
    if ((t & 15) == 0){
      const int row = bm + tm + i;
      if (row < nrows){ atomicAdd(&ssrc[row], ps); atomicAdd(&sdst[row], pd); }
    }
  }
}

__device__ __forceinline__ void split_ids2(int bid, int GN, int auxn, int& g, int& aux){
  g = -1; aux = -1;
  const int nmin = (GN < auxn) ? GN : auxn;
  if (bid < 2*nmin){ if (bid & 1) aux = bid >> 1; else g = bid >> 1; }
  else {
    int r = bid - 2*nmin;
    if (GN > auxn) g = nmin + r; else aux = nmin + r;
  }
}

// ---------------- K1: gemm1 part A + passB slab partition ----------------
__global__ __launch_bounds__(256) void k_g1_pb(const float* __restrict__ A, const float* __restrict__ W,
                                               unsigned short* __restrict__ hb,
                                               const float* __restrict__ a_s, const float* __restrict__ a_d,
                                               float* __restrict__ ssrc, float* __restrict__ sdst,
                                               const int* __restrict__ ei, int* __restrict__ bcnt,
                                               uint2* __restrict__ staging){
  __shared__ __align__(16) char um[14856];   // union: gemm tiles (8704) | passB structures
  const int t = threadIdx.x;
  int g, aux;
  split_ids2(blockIdx.x, G1N, PBBN, g, aux);
  if (g >= 0){
    float (*As)[68] = reinterpret_cast<float(*)[68]>(um);
    float (*Ws)[68] = reinterpret_cast<float(*)[68]>(um + 4352);
    gemm_tile<IN_>(As, Ws, A, W, hb, N_, a_s, a_d, ssrc, sdst, g % NMT, g / NMT, t);
    return;
  }
  uint2* slots = reinterpret_cast<uint2*>(um);          // 1563*8 = 12504
  int* hist  = reinterpret_cast<int*>(um + 12504);      // 196
  int* lbase = reinterpret_cast<int*>(um + 13288);      // 196
  int* cur2  = reinterpret_cast<int*>(um + 14072);      // 196
  const int e0 = aux*EB2;
  const int e1 = min(e0 + EB2, E_);
  if (t < NBKT) hist[t] = 0;
  __syncthreads();
  for (int e = e0 + t; e < e1; e += 256)
    atomicAdd(&hist[((unsigned)ei[E_ + e]) >> BSH], 1);
  __syncthreads();
  if (t < NBKT) lbase[t] = hist[t];
  __syncthreads();
  for (int o = 1; o < NBKT; o <<= 1){
    int x = (t >= o && t < NBKT) ? lbase[t-o] : 0;
    __syncthreads();
    if (t < NBKT) lbase[t] += x;
    __syncthreads();
  }
  int excl = 0;
  if (t < NBKT) excl = lbase[t] - hist[t];
  __syncthreads();
  if (t < NBKT){ lbase[t] = excl; cur2[t] = excl; }
  __syncthreads();
  for (int e = e0 + t; e < e1; e += 256){
    const int s = ei[e], d = ei[E_ + e];
    const int b = ((unsigned)d) >> BSH;
    const int slot = atomicAdd(&cur2[b], 1);
    slots[slot] = make_uint2((unsigned)s, (unsigned)d);
  }
  __syncthreads();
  if (t < NBKT){
    const int c = cur2[t] - lbase[t];
    hist[t] = (c > 0) ? atomicAdd(&bcnt[t], c) : 0;    // hist := base within slab
  }
  __syncthreads();
  const int total = e1 - e0;
  for (int i = t; i < total; i += 256){
    const uint2 u = slots[i];
    const int b = u.y >> BSH;
    staging[(size_t)b*SLAB + hist[b] + (i - lbase[b])] = u;   // coalesced runs
  }
}

// ---------------- K2: gemm1 part B + passC per-bucket counting sort ----------------
__global__ __launch_bounds__(256) void k_g1_pc(const float* __restrict__ A, const float* __restrict__ W,
                                               unsigned short* __restrict__ hb,
                                               const float* __restrict__ a_s, const float* __restrict__ a_d,
                                               float* __restrict__ ssrc, float* __restrict__ sdst,
                                               const uint2* __restrict__ staging, const int* __restrict__ bcnt,
                                               const int* __restrict__ bpre, int* __restrict__ rowp,
                                               int* __restrict__ col){
  __shared__ __align__(16) char um[8704];   // union: gemm tiles | passC (h2[512]+cur[512]=4096)
  const int t = threadIdx.x;
  int g, aux;
  split_ids2(blockIdx.x, G2N, NBKT, g, aux);
  if (g >= 0){
    float (*As)[68] = reinterpret_cast<float(*)[68]>(um);
    float (*Ws)[68] = reinterpret_cast<float(*)[68]>(um + 4352);
    const int gg = G1N + g;
    gemm_tile<IN_>(As, Ws, A, W, hb, N_, a_s, a_d, ssrc, sdst, gg % NMT, gg / NMT, t);
    return;
  }
  int* h2  = reinterpret_cast<int*>(um);          // [512] degree counts
  int* cur = reinterpret_cast<int*>(um + 2048);   // [512] global col cursors
  const int b   = aux;
  const int lo  = b << BSH;
  const int hi  = min(lo + BW_, N_);
  const int nn  = hi - lo;
  const int cb  = bcnt[b];
  const int pre = bpre[b];
  const uint2* slab = staging + (size_t)b*SLAB;
  h2[t] = 0; h2[t+256] = 0;
  __syncthreads();
  for (int i = t; i < cb; i += 256)
    atomicAdd(&h2[(int)slab[i].y - lo], 1);
  __syncthreads();
  const int a0 = h2[t], a1 = h2[t+256];
  for (int o = 1; o < 512; o <<= 1){
    const int x0 = (t >= o) ? h2[t-o] : 0;
    const int x1 = (t+256 >= o) ? h2[t+256-o] : 0;
    __syncthreads();
    h2[t] += x0; h2[t+256] += x1;
    __syncthreads();
  }
  if (t < nn){
    const int rp = pre + lo + t + (h2[t] - a0);
    rowp[lo + t] = rp;
    col[rp] = lo + t;
    cur[t] = rp + 1;
  }
  const int j1 = t + 256;
  if (j1 < nn){
    const int rp = pre + lo + j1 + (h2[j1] - a1);
    rowp[lo + j1] = rp;
    col[rp] = lo + j1;
    cur[j1] = rp + 1;
  }
  if (b == NBKT-1 && t == 0) rowp[N_] = E_ + N_;
  __syncthreads();
  for (int i = t; i < cb; i += 256){
    const uint2 u = slab[i];
    const int pos = atomicAdd(&cur[(int)u.y - lo], 1);
    col[pos] = (int)u.x;
  }
}

// ---------------- gemm2: bf16 MFMA (D = A_bf16 · (W_hi+W_lo), BN1+relu fused on A) ----------------
// A arrives as bf16 (agg1 output); after BN+relu it is rounded to bf16 once -> A exact in bf16,
// so only 2 MFMA products (W split) are needed.
__global__ __launch_bounds__(256) void k_gemm2_mfma(const unsigned short* __restrict__ Ab,
                                                    const unsigned short* __restrict__ Wt_hi,
                                                    const unsigned short* __restrict__ Wt_lo,
                                                    unsigned short* __restrict__ hb,
                                                    const float* __restrict__ a_s, const float* __restrict__ a_d,
                                                    float* __restrict__ ssrc, float* __restrict__ sdst,
                                                    const float* __restrict__ bnsc, const float* __restrict__ bnsh){
  __shared__ short As_s[64][40];
  const int t = threadIdx.x;
  const int lane = t & 63;
  const int w = t >> 6;
  const int l15 = lane & 15;
  const int lk  = lane >> 4;
  const int m0 = blockIdx.x * 64;
  const int srow = t >> 2;
  const int skq  = (t & 3) * 8;
  f32x4 acc[4][4];
  #pragma unroll
  for (int fm=0; fm<4; fm++)
    #pragma unroll
    for (int fn=0; fn<4; fn++) acc[fm][fn] = (f32x4)0.f;
  float4 asv[4], adv[4];
  #pragma unroll
  for (int fn=0; fn<4; fn++){
    asv[fn] = *reinterpret_cast<const float4*>(a_s + w*64 + fn*16 + lk*4);
    adv[fn] = *reinterpret_cast<const float4*>(a_d + w*64 + fn*16 + lk*4);
  }
  const int arow = m0 + srow;
  for (int kb = 0; kb < 256; kb += 32){
    float v[8];
    if (arow < N_){
      const uint4 q = *reinterpret_cast<const uint4*>(Ab + (size_t)arow*256 + kb + skq);
      const float4 s0 = *reinterpret_cast<const float4*>(bnsc + kb + skq);
      const float4 s1 = *reinterpret_cast<const float4*>(bnsc + kb + skq + 4);
      const float4 h0 = *reinterpret_cast<const float4*>(bnsh + kb + skq);
      const float4 h1 = *reinterpret_cast<const float4*>(bnsh + kb + skq + 4);
      v[0]=fmaxf(bflo(q.x)*s0.x+h0.x,0.f); v[1]=fmaxf(bfhi(q.x)*s0.y+h0.y,0.f);
      v[2]=fmaxf(bflo(q.y)*s0.z+h0.z,0.f); v[3]=fmaxf(bfhi(q.y)*s0.w+h0.w,0.f);
      v[4]=fmaxf(bflo(q.z)*s1.x+h1.x,0.f); v[5]=fmaxf(bfhi(q.z)*s1.y+h1.y,0.f);
      v[6]=fmaxf(bflo(q.w)*s1.z+h1.z,0.f); v[7]=fmaxf(bfhi(q.w)*s1.w+h1.w,0.f);
    } else {
      #pragma unroll
      for (int j=0;j<8;j++) v[j]=0.f;
    }
    unsigned hh[4];
    #pragma unroll
    for (int j=0;j<4;j++){
      const unsigned short ha = f2bf(v[2*j]), hb_ = f2bf(v[2*j+1]);
      hh[j] = (unsigned)ha | ((unsigned)hb_ << 16);
    }
    __syncthreads();
    *reinterpret_cast<uint4*>(&As_s[srow][skq]) = make_uint4(hh[0],hh[1],hh[2],hh[3]);
    __syncthreads();
    bf8v afh[4], afl[4];
    #pragma unroll
    for (int fn=0; fn<4; fn++){
      const size_t nrow = (size_t)(w*64 + fn*16 + l15);
      afh[fn] = *reinterpret_cast<const bf8v*>(Wt_hi + nrow*256 + kb + lk*8);
      afl[fn] = *reinterpret_cast<const bf8v*>(Wt_lo + nrow*256 + kb + lk*8);
    }
    #pragma unroll
    for (int fm=0; fm<4; fm++){
      const bf8v bb = *reinterpret_cast<const bf8v*>(&As_s[fm*16 + l15][lk*8]);
      #pragma unroll
      for (int fn=0; fn<4; fn++){
        acc[fm][fn] = __builtin_amdgcn_mfma_f32_16x16x32_bf16(afh[fn], bb, acc[fm][fn], 0,0,0);
        acc[fm][fn] = __builtin_amdgcn_mfma_f32_16x16x32_bf16(afl[fn], bb, acc[fm][fn], 0,0,0);
      }
    }
  }
  #pragma unroll
  for (int fm=0; fm<4; fm++){
    const int m = m0 + fm*16 + l15;
    float ps = 0.f, pd = 0.f;
    #pragma unroll
    for (int fn=0; fn<4; fn++){
      const f32x4 c = acc[fm][fn];
      ps += c[0]*asv[fn].x + c[1]*asv[fn].y + c[2]*asv[fn].z + c[3]*asv[fn].w;
      pd += c[0]*adv[fn].x + c[1]*adv[fn].y + c[2]*adv[fn].z + c[3]*adv[fn].w;
      if (m < N_){
        ushort4 o;
        o.x = f2bf(c[0]); o.y = f2bf(c[1]); o.z = f2bf(c[2]); o.w = f2bf(c[3]);
        *reinterpret_cast<ushort4*>(hb + (size_t)m*256 + w*64 + fn*16 + lk*4) = o;
      }
    }
    ps += __shfl_xor(ps, 16, 64); ps += __shfl_xor(ps, 32, 64);
    pd += __shfl_xor(pd, 16, 64); pd += __shfl_xor(pd, 32, 64);
    if (lk == 0 && m < N_){
      atomicAdd(&ssrc[m], ps);
      atomicAdd(&sdst[m], pd);
    }
  }
}

// ---------------- GAT aggregation (R5-proven) + fused BN stats; bf16 output ----------------
__global__ __launch_bounds__(256) void k_agg(const unsigned short* __restrict__ hb, const int* __restrict__ col,
                                             const int* __restrict__ rowp, const float* __restrict__ ssrc,
                                             const float* __restrict__ sdst, const float* __restrict__ bias,
                                             unsigned short* __restrict__ outb, float* __restrict__ bnsum,
                                             float* __restrict__ bnsq){
  __shared__ float sbn[512];
  __shared__ __align__(16) float2 wsb[4][64];
  const int t = threadIdx.x;
  sbn[t] = 0.f; sbn[t+256] = 0.f;
  const int lane = t & 63;
  const int wid  = t >> 6;
  const int fo = lane*4;
  const float4 bb = *reinterpret_cast<const float4*>(bias + fo);
  float s0=0.f,s1=0.f,s2=0.f,s3=0.f, q0=0.f,q1=0.f,q2=0.f,q3=0.f;
  __syncthreads();
  for (int node = blockIdx.x*4 + wid; node < N_; node += gridDim.x*4){
    const int start = rowp[node];
    const int end   = rowp[node+1];
    const float sd  = sdst[node];
    float den_l = 0.f;
    float ax=0.f, ay=0.f, az=0.f, aw=0.f;
    float bx=0.f, by=0.f, bz=0.f, bw=0.f;
    for (int base = start; base < end; base += 64){
      const int p = base + lane;
      float w = 0.f; int s = 0;
      if (p < end){
        s = col[p];
        float e = ssrc[s] + sd;
        e = e > 0.f ? e : 0.2f*e;
        w = expf(e);
      }
      den_l += w;
      wsb[wid][lane] = make_float2(w, __int_as_float(s));
      const int m = (end - base < 64) ? (end - base) : 64;
      int j = 0;
      for (; j + 2 <= m; j += 2){
        const float4 q = *reinterpret_cast<const float4*>(&wsb[wid][j]);
        const float w0 = q.x; const int v0 = __float_as_int(q.y);
        const float w1 = q.z; const int v1 = __float_as_int(q.w);
        const ushort4 h0 = *reinterpret_cast<const ushort4*>(hb + (size_t)v0*256 + fo);
        const ushort4 h1 = *reinterpret_cast<const ushort4*>(hb + (size_t)v1*256 + fo);
        ax += w0*bf2f(h0.x); ay += w0*bf2f(h0.y); az += w0*bf2f(h0.z); aw += w0*bf2f(h0.w);
        bx += w1*bf2f(h1.x); by += w1*bf2f(h1.y); bz += w1*bf2f(h1.z); bw += w1*bf2f(h1.w);
      }
      if (j < m){
        const float2 q = wsb[wid][j];
        const float w0 = q.x; const int v0 = __float_as_int(q.y);
        const ushort4 h0 = *reinterpret_cast<const ushort4*>(hb + (size_t)v0*256 + fo);
        ax += w0*bf2f(h0.x); ay += w0*bf2f(h0.y); az += w0*bf2f(h0.z); aw += w0*bf2f(h0.w);
      }
    }
    float den = den_l;
    #pragma unroll
    for (int o = 32; o; o >>= 1) den += __shfl_xor(den, o, 64);
    const float inv = 1.f/den;
    float4 r;
    r.x = (ax+bx)*inv + bb.x;
    r.y = (ay+by)*inv + bb.y;
    r.z = (az+bz)*inv + bb.z;
    r.w = (aw+bw)*inv + bb.w;
    ushort4 o;
    o.x = f2bf(r.x); o.y = f2bf(r.y); o.z = f2bf(r.z); o.w = f2bf(r.w);
    *reinterpret_cast<ushort4*>(outb + (size_t)node*256 + fo) = o;
    s0 += r.x; s1 += r.y; s2 += r.z; s3 += r.w;
    q0 += r.x*r.x; q1 += r.y*r.y; q2 += r.z*r.z; q3 += r.w*r.w;
  }
  atomicAdd(&sbn[fo+0], s0); atomicAdd(&sbn[fo+1], s1);
  atomicAdd(&sbn[fo+2], s2); atomicAdd(&sbn[fo+3], s3);
  atomicAdd(&sbn[256+fo+0], q0); atomicAdd(&sbn[256+fo+1], q1);
  atomicAdd(&sbn[256+fo+2], q2); atomicAdd(&sbn[256+fo+3], q3);
  __syncthreads();
  atomicAdd(&bnsum[t], sbn[t]);
  atomicAdd(&bnsq[t],  sbn[256+t]);
}

__global__ void k_bnprep(const float* __restrict__ g, const float* __restrict__ be,
                         float* __restrict__ bsum, float* __restrict__ bsq){
  const int f = threadIdx.x;
  const float mean = bsum[f] * (1.0f/N_);
  const float var  = bsq[f]  * (1.0f/N_) - mean*mean;
  const float sc = g[f] / sqrtf(var + EPSV);
  bsum[f] = sc;
  bsq[f]  = be[f] - mean*sc;
}

// ---------------- global mean pool (fused BN2+relu), bf16 input ----------------
__global__ __launch_bounds__(256) void k_pool(const unsigned short* __restrict__ x, const int* __restrict__ batch,
                                              const float* __restrict__ sc, const float* __restrict__ sh,
                                              float* __restrict__ psum, float* __restrict__ pcnt){
  const int f = threadIdx.x;
  const float scf = sc[f], shf = sh[f];
  const int RPB = (N_ + gridDim.x - 1) / gridDim.x;
  const int r0 = blockIdx.x * RPB;
  const int r1 = min(r0 + RPB, N_);
  if (r0 >= N_) return;
  float local = 0.f, c = 0.f;
  int curg = -1;
  for (int r = r0; r < r1; ++r){
    const int g = batch[r];
    if (g != curg){
      if (curg >= 0){
        atomicAdd(&psum[curg*256 + f], local);
        if (f == 0) atomicAdd(&pcnt[curg], c);
      }
      curg = g; local = 0.f; c = 0.f;
    }
    local += fmaxf(bf2f(x[(size_t)r*256 + f])*scf + shf, 0.f);
    c += 1.f;
  }
  if (curg >= 0){
    atomicAdd(&psum[curg*256 + f], local);
    if (f == 0) atomicAdd(&pcnt[curg], c);
  }
}

// ---------------- FC head ----------------
__global__ __launch_bounds__(256) void k_fc1(const float* __restrict__ psum, const float* __restrict__ pcnt,
                                             const float* __restrict__ w, const float* __restrict__ b,
                                             float* __restrict__ z){
  __shared__ float p[256];
  const int g = blockIdx.x, f = threadIdx.x;
  const float cnt = fmaxf(pcnt[g], 1.f);
  p[f] = psum[g*256 + f] / cnt;
  __syncthreads();
  float acc = b[f];
  #pragma unroll 8
  for (int k = 0; k < 256; ++k) acc += p[k] * w[k*256 + f];
  z[g*256 + f] = fmaxf(acc, 0.f);
}

__global__ __launch_bounds__(128) void k_fc2(const float* __restrict__ zin, const float* __restrict__ w,
                                             const float* __restrict__ b, float* __restrict__ z){
  __shared__ float p[256];
  const int g = blockIdx.x, f = threadIdx.x;
  p[f] = zin[g*256 + f];
  p[f+128] = zin[g*256 + f + 128];
  __syncthreads();
  float acc = b[f];
  #pragma unroll 8
  for (int k = 0; k < 256; ++k) acc += p[k] * w[k*128 + f];
  z[g*128 + f] = fmaxf(acc, 0.f);
}

__global__ __launch_bounds__(64) void k_fc3(const float* __restrict__ zin, const float* __restrict__ w,
                                            const float* __restrict__ b, float* __restrict__ out){
  const int g = threadIdx.x;   // 64 graphs
  float acc = b[0];
  #pragma unroll 8
  for (int k = 0; k < 128; ++k) acc += zin[g*128 + k] * w[k];
  out[g] = acc;
}

// ---------------- launch ----------------
extern "C" void kernel_launch(void* const* d_in, const int* in_sizes, int n_in,
                              void* d_out, int out_size, void* d_ws, size_t ws_size,
                              hipStream_t stream){
  (void)in_sizes; (void)n_in; (void)out_size; (void)ws_size;
  const float* x    = (const float*)d_in[0];
  const float* W1   = (const float*)d_in[1];
  const float* a_s1 = (const float*)d_in[2];
  const float* a_d1 = (const float*)d_in[3];
  const float* b1   = (const float*)d_in[4];
  const float* g1   = (const float*)d_in[5];
  const float* be1  = (const float*)d_in[6];
  const float* W2   = (const float*)d_in[7];
  const float* a_s2 = (const float*)d_in[8];
  const float* a_d2 = (const float*)d_in[9];
  const float* b2   = (const float*)d_in[10];
  const float* g2   = (const float*)d_in[11];
  const float* be2  = (const float*)d_in[12];
  const float* fc1w = (const float*)d_in[13];
  const float* fc1b = (const float*)d_in[14];
  const float* fc2w = (const float*)d_in[15];
  const float* fc2b = (const float*)d_in[16];
  const float* fc3w = (const float*)d_in[17];
  const float* fc3b = (const float*)d_in[18];
  const int*   ei   = (const int*)d_in[19];
  const int*   batch= (const int*)d_in[20];
  float* out = (float*)d_out;

  char* ws = (char*)d_ws;
  size_t off = 0;
  auto alloc = [&](size_t bytes)->char*{
    char* p = ws + off;
    off += (bytes + 255) & ~(size_t)255;
    return p;
  };
  unsigned short* hb  = (unsigned short*)alloc((size_t)N_*256*2);
  unsigned short* agg = (unsigned short*)alloc((size_t)N_*256*2);   // bf16 agg output
  uint2* staging= (uint2*)alloc((size_t)NBKT*SLAB*8);   // 32.1 MB slabs
  int*   col    = (int*)  alloc((size_t)(E_+N_)*4);
  int*   rowp   = (int*)  alloc((size_t)(N_+1)*4);
  int*   bcnt   = (int*)  alloc(NBKT*4);
  int*   bpre   = (int*)  alloc(NBKT*4);
  unsigned short* wt_hi = (unsigned short*)alloc(256*256*2);
  unsigned short* wt_lo = (unsigned short*)alloc(256*256*2);
  float* ssrc   = (float*)alloc((size_t)N_*4);
  float* sdst   = (float*)alloc((size_t)N_*4);
  float* bns1   = (float*)alloc(512*4);
  float* bns2   = (float*)alloc(512*4);
  float* pooled = (float*)alloc((G_*256 + G_)*4);
  float* z1     = (float*)alloc(G_*256*4);
  float* z2     = (float*)alloc(G_*128*4);

  // ---- W2 transpose+split (no deps) ----
  k_prepw<<<256, 256, 0, stream>>>(W2, wt_hi, wt_lo);

  // ---- K1: gemm1 part A + slab partition ----
  hipMemsetAsync(bcnt, 0, NBKT*4, stream);
  hipMemsetAsync(ssrc, 0, (size_t)N_*4, stream);
  hipMemsetAsync(sdst, 0, (size_t)N_*4, stream);
  hipMemsetAsync(bns1, 0, 512*4, stream);
  k_g1_pb<<<G1N + PBBN, 256, 0, stream>>>(x, W1, hb, a_s1, a_d1, ssrc, sdst, ei, bcnt, staging);

  // ---- slab prefix ----
  k_bscan<<<1, 256, 0, stream>>>(bcnt, bpre);

  // ---- K2: gemm1 part B + per-bucket counting sort (rowp + col) ----
  k_g1_pc<<<G2N + NBKT, 256, 0, stream>>>(x, W1, hb, a_s1, a_d1, ssrc, sdst, staging, bcnt, bpre, rowp, col);

  // ---- layer 1 aggregation (+BN1 stats) ----
  k_agg<<<2048, 256, 0, stream>>>(hb, col, rowp, ssrc, sdst, b1, agg, bns1, bns1 + 256);
  k_bnprep<<<1, 256, 0, stream>>>(g1, be1, bns1, bns1 + 256);

  // ---- layer 2: bf16 MFMA GEMM (BN1+relu fused on A-load; 2-product W split) ----
  hipMemsetAsync(ssrc, 0, (size_t)N_*4, stream);
  hipMemsetAsync(sdst, 0, (size_t)N_*4, stream);
  hipMemsetAsync(bns2, 0, 512*4, stream);
  k_gemm2_mfma<<<NMT, 256, 0, stream>>>(agg, wt_hi, wt_lo, hb, a_s2, a_d2, ssrc, sdst, bns1, bns1 + 256);
  k_agg<<<2048, 256, 0, stream>>>(hb, col, rowp, ssrc, sdst, b2, agg, bns2, bns2 + 256);
  k_bnprep<<<1, 256, 0, stream>>>(g2, be2, bns2, bns2 + 256);

  // ---- pool (BN2+relu fused, bf16 in) + head ----
  hipMemsetAsync(pooled, 0, (size_t)(G_*256 + G_)*4, stream);
  k_pool<<<512, 256, 0, stream>>>(agg, batch, bns2, bns2 + 256, pooled, pooled + G_*256);
  k_fc1<<<G_, 256, 0, stream>>>(pooled, pooled + G_*256, fc1w, fc1b, z1);
  k_fc2<<<G_, 128, 0, stream>>>(z1, fc2w, fc2b, z2);
  k_fc3<<<1, 64, 0, stream>>>(z2, fc3w, fc3b, out);
}

// Round 12
// 866.309 us; speedup vs baseline: 1.4003x; 1.0097x over previous
//
#include <hip/hip_runtime.h>
#include <hip/hip_bf16.h>

#define N_   100000
#define E_   3200000
#define IN_  128
#define H_   256
#define OUT_ 256
#define G_   64
#define EPSV 1e-5f

#define NMT   1563            // ceil(N/64) M-tiles; 4 col tiles -> 6252 gemm1 blocks
#define EB2   1563            // edges per passB block (2048*1563 >= E)
#define PBBN  2048            // passB aux blocks
#define NBKT  196             // 512-node buckets (196*512 >= N)
#define BSH   9
#define BW_   512
#define SLAB  20480           // slab capacity (mean 16384 + 32 sigma)
#define G1N   4200            // gemm1 ids in K1 (passB is the longer tail -> more cover)
#define G2N   2052            // gemm1 ids in K2

typedef short bf8v __attribute__((ext_vector_type(8)));
typedef float f32x4 __attribute__((ext_vector_type(4)));

__device__ __forceinline__ unsigned short f2bf(float x){
  unsigned u = __float_as_uint(x);
  return (unsigned short)((u + 0x7FFFu + ((u >> 16) & 1u)) >> 16);
}
__device__ __forceinline__ float bf2f(unsigned short u){
  return __uint_as_float(((unsigned)u) << 16);
}
__device__ __forceinline__ float bflo(unsigned v){ return __uint_as_float(v << 16); }
__device__ __forceinline__ float bfhi(unsigned v){ return __uint_as_float(v & 0xffff0000u); }

// ---------------- init: W2 transpose+split, zero ssrc/sdst/bns1/bcnt ----------------
__global__ __launch_bounds__(256) void k_init(const float* __restrict__ W,
                                              unsigned short* __restrict__ Wt_hi,
                                              unsigned short* __restrict__ Wt_lo,
                                              float* __restrict__ ssrc, float* __restrict__ sdst,
                                              float* __restrict__ bns1, int* __restrict__ bcnt){
  const int bid = blockIdx.x, t = threadIdx.x;
  if (bid < 256){
    const float v = W[bid*256 + t];
    const unsigned short h = f2bf(v);
    Wt_hi[t*256 + bid] = h;
    Wt_lo[t*256 + bid] = f2bf(v - bf2f(h));
  }
  const int idx = bid*256 + t;
  if (idx < N_){ ssrc[idx] = 0.f; sdst[idx] = 0.f; }
  if (bid == 256){
    bns1[t] = 0.f; bns1[t+256] = 0.f;
    if (t < NBKT) bcnt[t] = 0;
  }
}

// ---------------- slab-count exclusive prefix (196 values, 1 block) ----------------
__global__ void k_bscan(const int* __restrict__ bcnt, int* __restrict__ bpre){
  __shared__ int s[256];
  const int t = threadIdx.x;
  const int v = (t < NBKT) ? bcnt[t] : 0;
  s[t] = v;
  __syncthreads();
  for (int o = 1; o < 256; o <<= 1){
    int x = (t >= o) ? s[t-o] : 0;
    __syncthreads();
    s[t] += x;
    __syncthreads();
  }
  if (t < NBKT) bpre[t] = s[t] - v;
}

// ---------------- shared fp32 GEMM tile body (gemm1 / cover role) ----------------
template<int K>
__device__ __forceinline__ void gemm_tile(float (*As)[68], float (*Ws)[68],
                                          const float* __restrict__ A, const float* __restrict__ W,
                                          unsigned short* __restrict__ hb, int nrows,
                                          const float* __restrict__ a_s, const float* __restrict__ a_d,
                                          float* __restrict__ ssrc, float* __restrict__ sdst,
                                          int bx, int by, int t){
  const int bm = bx * 64;
  const int bn = by * 64;
  const int lm = t >> 2,  lk = (t & 3) * 4;
  const int wk = t >> 4,  wn = (t & 15) * 4;
  const int tm = (t >> 4) * 4, tn = (t & 15) * 4;
  float acc[4][4];
  #pragma unroll
  for (int i=0;i<4;i++){
    #pragma unroll
    for (int j=0;j<4;j++) acc[i][j]=0.f;
  }
  for (int kb = 0; kb < K; kb += 16){
    const int arow = bm + lm;
    float4 av = make_float4(0.f,0.f,0.f,0.f);
    if (arow < nrows){
      av = *reinterpret_cast<const float4*>(A + (size_t)arow*K + kb + lk);
    }
    const float4 wv = *reinterpret_cast<const float4*>(W + (size_t)(kb + wk)*256 + bn + wn);
    __syncthreads();
    As[lk+0][lm]=av.x; As[lk+1][lm]=av.y; As[lk+2][lm]=av.z; As[lk+3][lm]=av.w;
    *reinterpret_cast<float4*>(&Ws[wk][wn]) = wv;
    __syncthreads();
    #pragma unroll
    for (int k=0;k<16;k++){
      const float4 a  = *reinterpret_cast<const float4*>(&As[k][tm]);
      const float4 bv = *reinterpret_cast<const float4*>(&Ws[k][tn]);
      acc[0][0]+=a.x*bv.x; acc[0][1]+=a.x*bv.y; acc[0][2]+=a.x*bv.z; acc[0][3]+=a.x*bv.w;
      acc[1][0]+=a.y*bv.x; acc[1][1]+=a.y*bv.y; acc[1][2]+=a.y*bv.z; acc[1][3]+=a.y*bv.w;
      acc[2][0]+=a.z*bv.x; acc[2][1]+=a.z*bv.y; acc[2][2]+=a.z*bv.z; acc[2][3]+=a.z*bv.w;
      acc[3][0]+=a.w*bv.x; acc[3][1]+=a.w*bv.y; acc[3][2]+=a.w*bv.z; acc[3][3]+=a.w*bv.w;
    }
  }
  #pragma unroll
  for (int i=0;i<4;i++){
    const int row = bm + tm + i;
    if (row < nrows){
      ushort4 o;
      o.x = f2bf(acc[i][0]); o.y = f2bf(acc[i][1]);
      o.z = f2bf(acc[i][2]); o.w = f2bf(acc[i][3]);
      *reinterpret_cast<ushort4*>(hb + (size_t)row*256 + bn + tn) = o;
    }
  }
  const float4 asv = *reinterpret_cast<const float4*>(a_s + bn + tn);
  const float4 adv = *reinterpret_cast<const float4*>(a_d + bn + tn);
  #pragma unroll
  for (int i=0;i<4;i++){
    float ps = acc[i][0]*asv.x + acc[i][1]*asv.y + acc[i][2]*asv.z + acc[i][3]*asv.w;
    float pd = acc[i][0]*adv.x + acc[i][1]*adv.y + acc[i][2]*adv.z + acc[i][3]*adv.w;
    #pragma unroll
    for (int o=1;o<16;o<<=1){ ps += __shfl_xor(ps, o, 64); pd += __shfl_xor(pd, o, 64); }
    if ((t & 15) == 0){
      const int row = bm + tm + i;
      if (row < nrows){ atomicAdd(&ssrc[row], ps); atomicAdd(&sdst[row], pd); }
    }
  }
}

__device__ __forceinline__ void split_ids2(int bid, int GN, int auxn, int& g, int& aux){
  g = -1; aux = -1;
  const int nmin = (GN < auxn) ? GN : auxn;
  if (bid < 2*nmin){ if (bid & 1) aux = bid >> 1; else g = bid >> 1; }
  else {
    int r = bid - 2*nmin;
    if (GN > auxn) g = nmin + r; else aux = nmin + r;
  }
}

// ---------------- K1: gemm1 part A + passB slab partition ----------------
__global__ __launch_bounds__(256) void k_g1_pb(const float* __restrict__ A, const float* __restrict__ W,
                                               unsigned short* __restrict__ hb,
                                               const float* __restrict__ a_s, const float* __restrict__ a_d,
                                               float* __restrict__ ssrc, float* __restrict__ sdst,
                                               const int* __restrict__ ei, int* __restrict__ bcnt,
                                               uint2* __restrict__ staging){
  __shared__ __align__(16) char um[14856];   // union: gemm tiles (8704) | passB structures
  const int t = threadIdx.x;
  int g, aux;
  split_ids2(blockIdx.x, G1N, PBBN, g, aux);
  if (g >= 0){
    float (*As)[68] = reinterpret_cast<float(*)[68]>(um);
    float (*Ws)[68] = reinterpret_cast<float(*)[68]>(um + 4352);
    gemm_tile<IN_>(As, Ws, A, W, hb, N_, a_s, a_d, ssrc, sdst, g % NMT, g / NMT, t);
    return;
  }
  uint2* slots = reinterpret_cast<uint2*>(um);          // 1563*8 = 12504
  int* hist  = reinterpret_cast<int*>(um + 12504);      // 196
  int* lbase = reinterpret_cast<int*>(um + 13288);      // 196
  int* cur2  = reinterpret_cast<int*>(um + 14072);      // 196
  const int e0 = aux*EB2;
  const int e1 = min(e0 + EB2, E_);
  if (t < NBKT) hist[t] = 0;
  __syncthreads();
  for (int e = e0 + t; e < e1; e += 256)
    atomicAdd(&hist[((unsigned)ei[E_ + e]) >> BSH], 1);
  __syncthreads();
  if (t < NBKT) lbase[t] = hist[t];
  __syncthreads();
  for (int o = 1; o < NBKT; o <<= 1){
    int x = (t >= o && t < NBKT) ? lbase[t-o] : 0;
    __syncthreads();
    if (t < NBKT) lbase[t] += x;
    __syncthreads();
  }
  int excl = 0;
  if (t < NBKT) excl = lbase[t] - hist[t];
  __syncthreads();
  if (t < NBKT){ lbase[t] = excl; cur2[t] = excl; }
  __syncthreads();
  for (int e = e0 + t; e < e1; e += 256){
    const int s = ei[e], d = ei[E_ + e];
    const int b = ((unsigned)d) >> BSH;
    const int slot = atomicAdd(&cur2[b], 1);
    slots[slot] = make_uint2((unsigned)s, (unsigned)d);
  }
  __syncthreads();
  if (t < NBKT){
    const int c = cur2[t] - lbase[t];
    hist[t] = (c > 0) ? atomicAdd(&bcnt[t], c) : 0;    // hist := base within slab
  }
  __syncthreads();
  const int total = e1 - e0;
  for (int i = t; i < total; i += 256){
    const uint2 u = slots[i];
    const int b = u.y >> BSH;
    staging[(size_t)b*SLAB + hist[b] + (i - lbase[b])] = u;   // coalesced runs
  }
}

// ---------------- K2: gemm1 part B + passC per-bucket counting sort ----------------
__global__ __launch_bounds__(256) void k_g1_pc(const float* __restrict__ A, const float* __restrict__ W,
                                               unsigned short* __restrict__ hb,
                                               const float* __restrict__ a_s, const float* __restrict__ a_d,
                                               float* __restrict__ ssrc, float* __restrict__ sdst,
                                               const uint2* __restrict__ staging, const int* __restrict__ bcnt,
                                               const int* __restrict__ bpre, int* __restrict__ rowp,
                                               int* __restrict__ col){
  __shared__ __align__(16) char um[8704];   // union: gemm tiles | passC (h2[512]+cur[512]=4096)
  const int t = threadIdx.x;
  int g, aux;
  split_ids2(blockIdx.x, G2N, NBKT, g, aux);
  if (g >= 0){
    float (*As)[68] = reinterpret_cast<float(*)[68]>(um);
    float (*Ws)[68] = reinterpret_cast<float(*)[68]>(um + 4352);
    const int gg = G1N + g;
    gemm_tile<IN_>(As, Ws, A, W, hb, N_, a_s, a_d, ssrc, sdst, gg % NMT, gg / NMT, t);
    return;
  }
  int* h2  = reinterpret_cast<int*>(um);          // [512] degree counts
  int* cur = reinterpret_cast<int*>(um + 2048);   // [512] global col cursors
  const int b   = aux;
  const int lo  = b << BSH;
  const int hi  = min(lo + BW_, N_);
  const int nn  = hi - lo;
  const int cb  = bcnt[b];
  const int pre = bpre[b];
  const uint2* slab = staging + (size_t)b*SLAB;
  h2[t] = 0; h2[t+256] = 0;
  __syncthreads();
  for (int i = t; i < cb; i += 256)
    atomicAdd(&h2[(int)slab[i].y - lo], 1);
  __syncthreads();
  const int a0 = h2[t], a1 = h2[t+256];
  for (int o = 1; o < 512; o <<= 1){
    const int x0 = (t >= o) ? h2[t-o] : 0;
    const int x1 = (t+256 >= o) ? h2[t+256-o] : 0;
    __syncthreads();
    h2[t] += x0; h2[t+256] += x1;
    __syncthreads();
  }
  if (t < nn){
    const int rp = pre + lo + t + (h2[t] - a0);
    rowp[lo + t] = rp;
    col[rp] = lo + t;
    cur[t] = rp + 1;
  }
  const int j1 = t + 256;
  if (j1 < nn){
    const int rp = pre + lo + j1 + (h2[j1] - a1);
    rowp[lo + j1] = rp;
    col[rp] = lo + j1;
    cur[j1] = rp + 1;
  }
  if (b == NBKT-1 && t == 0) rowp[N_] = E_ + N_;
  __syncthreads();
  for (int i = t; i < cb; i += 256){
    const uint2 u = slab[i];
    const int pos = atomicAdd(&cur[(int)u.y - lo], 1);
    col[pos] = (int)u.x;
  }
}

// ---------------- gemm2: bf16 MFMA (D = A_bf16 · (W_hi+W_lo), BN1+relu fused on A) ----------------
__global__ __launch_bounds__(256) void k_gemm2_mfma(const unsigned short* __restrict__ Ab,
                                                    const unsigned short* __restrict__ Wt_hi,
                                                    const unsigned short* __restrict__ Wt_lo,
                                                    unsigned short* __restrict__ hb,
                                                    const float* __restrict__ a_s, const float* __restrict__ a_d,
                                                    float* __restrict__ ssrc, float* __restrict__ sdst,
                                                    const float* __restrict__ bnsc, const float* __restrict__ bnsh){
  __shared__ short As_s[64][40];
  const int t = threadIdx.x;
  const int lane = t & 63;
  const int w = t >> 6;
  const int l15 = lane & 15;
  const int lk  = lane >> 4;
  const int m0 = blockIdx.x * 64;
  const int srow = t >> 2;
  const int skq  = (t & 3) * 8;
  f32x4 acc[4][4];
  #pragma unroll
  for (int fm=0; fm<4; fm++)
    #pragma unroll
    for (int fn=0; fn<4; fn++) acc[fm][fn] = (f32x4)0.f;
  float4 asv[4], adv[4];
  #pragma unroll
  for (int fn=0; fn<4; fn++){
    asv[fn] = *reinterpret_cast<const float4*>(a_s + w*64 + fn*16 + lk*4);
    adv[fn] = *reinterpret_cast<const float4*>(a_d + w*64 + fn*16 + lk*4);
  }
  const int arow = m0 + srow;
  for (int kb = 0; kb < 256; kb += 32){
    float v[8];
    if (arow < N_){
      const uint4 q = *reinterpret_cast<const uint4*>(Ab + (size_t)arow*256 + kb + skq);
      const float4 s0 = *reinterpret_cast<const float4*>(bnsc + kb + skq);
      const float4 s1 = *reinterpret_cast<const float4*>(bnsc + kb + skq + 4);
      const float4 h0 = *reinterpret_cast<const float4*>(bnsh + kb + skq);
      const float4 h1 = *reinterpret_cast<const float4*>(bnsh + kb + skq + 4);
      v[0]=fmaxf(bflo(q.x)*s0.x+h0.x,0.f); v[1]=fmaxf(bfhi(q.x)*s0.y+h0.y,0.f);
      v[2]=fmaxf(bflo(q.y)*s0.z+h0.z,0.f); v[3]=fmaxf(bfhi(q.y)*s0.w+h0.w,0.f);
      v[4]=fmaxf(bflo(q.z)*s1.x+h1.x,0.f); v[5]=fmaxf(bfhi(q.z)*s1.y+h1.y,0.f);
      v[6]=fmaxf(bflo(q.w)*s1.z+h1.z,0.f); v[7]=fmaxf(bfhi(q.w)*s1.w+h1.w,0.f);
    } else {
      #pragma unroll
      for (int j=0;j<8;j++) v[j]=0.f;
    }
    unsigned hh[4];
    #pragma unroll
    for (int j=0;j<4;j++){
      const unsigned short ha = f2bf(v[2*j]), hb_ = f2bf(v[2*j+1]);
      hh[j] = (unsigned)ha | ((unsigned)hb_ << 16);
    }
    __syncthreads();
    *reinterpret_cast<uint4*>(&As_s[srow][skq]) = make_uint4(hh[0],hh[1],hh[2],hh[3]);
    __syncthreads();
    bf8v afh[4], afl[4];
    #pragma unroll
    for (int fn=0; fn<4; fn++){
      const size_t nrow = (size_t)(w*64 + fn*16 + l15);
      afh[fn] = *reinterpret_cast<const bf8v*>(Wt_hi + nrow*256 + kb + lk*8);
      afl[fn] = *reinterpret_cast<const bf8v*>(Wt_lo + nrow*256 + kb + lk*8);
    }
    #pragma unroll
    for (int fm=0; fm<4; fm++){
      const bf8v bb = *reinterpret_cast<const bf8v*>(&As_s[fm*16 + l15][lk*8]);
      #pragma unroll
      for (int fn=0; fn<4; fn++){
        acc[fm][fn] = __builtin_amdgcn_mfma_f32_16x16x32_bf16(afh[fn], bb, acc[fm][fn], 0,0,0);
        acc[fm][fn] = __builtin_amdgcn_mfma_f32_16x16x32_bf16(afl[fn], bb, acc[fm][fn], 0,0,0);
      }
    }
  }
  #pragma unroll
  for (int fm=0; fm<4; fm++){
    const int m = m0 + fm*16 + l15;
    float ps = 0.f, pd = 0.f;
    #pragma unroll
    for (int fn=0; fn<4; fn++){
      const f32x4 c = acc[fm][fn];
      ps += c[0]*asv[fn].x + c[1]*asv[fn].y + c[2]*asv[fn].z + c[3]*asv[fn].w;
      pd += c[0]*adv[fn].x + c[1]*adv[fn].y + c[2]*adv[fn].z + c[3]*adv[fn].w;
      if (m < N_){
        ushort4 o;
        o.x = f2bf(c[0]); o.y = f2bf(c[1]); o.z = f2bf(c[2]); o.w = f2bf(c[3]);
        *reinterpret_cast<ushort4*>(hb + (size_t)m*256 + w*64 + fn*16 + lk*4) = o;
      }
    }
    ps += __shfl_xor(ps, 16, 64); ps += __shfl_xor(ps, 32, 64);
    pd += __shfl_xor(pd, 16, 64); pd += __shfl_xor(pd, 32, 64);
    if (lk == 0 && m < N_){
      atomicAdd(&ssrc[m], ps);
      atomicAdd(&sdst[m], pd);
    }
  }
}

// ---------------- GAT aggregation (R5-proven) + fused BN stats; bf16 output ----------------
__global__ __launch_bounds__(256) void k_agg(const unsigned short* __restrict__ hb, const int* __restrict__ col,
                                             const int* __restrict__ rowp, const float* __restrict__ ssrc,
                                             const float* __restrict__ sdst, const float* __restrict__ bias,
                                             unsigned short* __restrict__ outb, float* __restrict__ bnsum,
                                             float* __restrict__ bnsq){
  __shared__ float sbn[512];
  __shared__ __align__(16) float2 wsb[4][64];
  const int t = threadIdx.x;
  sbn[t] = 0.f; sbn[t+256] = 0.f;
  const int lane = t & 63;
  const int wid  = t >> 6;
  const int fo = lane*4;
  const float4 bb = *reinterpret_cast<const float4*>(bias + fo);
  float s0=0.f,s1=0.f,s2=0.f,s3=0.f, q0=0.f,q1=0.f,q2=0.f,q3=0.f;
  __syncthreads();
  for (int node = blockIdx.x*4 + wid; node < N_; node += gridDim.x*4){
    const int start = rowp[node];
    const int end   = rowp[node+1];
    const float sd  = sdst[node];
    float den_l = 0.f;
    float ax=0.f, ay=0.f, az=0.f, aw=0.f;
    float bx=0.f, by=0.f, bz=0.f, bw=0.f;
    for (int base = start; base < end; base += 64){
      const int p = base + lane;
      float w = 0.f; int s = 0;
      if (p < end){
        s = col[p];
        float e = ssrc[s] + sd;
        e = e > 0.f ? e : 0.2f*e;
        w = expf(e);
      }
      den_l += w;
      wsb[wid][lane] = make_float2(w, __int_as_float(s));
      const int m = (end - base < 64) ? (end - base) : 64;
      int j = 0;
      for (; j + 2 <= m; j += 2){
        const float4 q = *reinterpret_cast<const float4*>(&wsb[wid][j]);
        const float w0 = q.x; const int v0 = __float_as_int(q.y);
        const float w1 = q.z; const int v1 = __float_as_int(q.w);
        const ushort4 h0 = *reinterpret_cast<const ushort4*>(hb + (size_t)v0*256 + fo);
        const ushort4 h1 = *reinterpret_cast<const ushort4*>(hb + (size_t)v1*256 + fo);
        ax += w0*bf2f(h0.x); ay += w0*bf2f(h0.y); az += w0*bf2f(h0.z); aw += w0*bf2f(h0.w);
        bx += w1*bf2f(h1.x); by += w1*bf2f(h1.y); bz += w1*bf2f(h1.z); bw += w1*bf2f(h1.w);
      }
      if (j < m){
        const float2 q = wsb[wid][j];
        const float w0 = q.x; const int v0 = __float_as_int(q.y);
        const ushort4 h0 = *reinterpret_cast<const ushort4*>(hb + (size_t)v0*256 + fo);
        ax += w0*bf2f(h0.x); ay += w0*bf2f(h0.y); az += w0*bf2f(h0.z); aw += w0*bf2f(h0.w);
      }
    }
    float den = den_l;
    #pragma unroll
    for (int o = 32; o; o >>= 1) den += __shfl_xor(den, o, 64);
    const float inv = 1.f/den;
    float4 r;
    r.x = (ax+bx)*inv + bb.x;
    r.y = (ay+by)*inv + bb.y;
    r.z = (az+bz)*inv + bb.z;
    r.w = (aw+bw)*inv + bb.w;
    ushort4 o;
    o.x = f2bf(r.x); o.y = f2bf(r.y); o.z = f2bf(r.z); o.w = f2bf(r.w);
    *reinterpret_cast<ushort4*>(outb + (size_t)node*256 + fo) = o;
    s0 += r.x; s1 += r.y; s2 += r.z; s3 += r.w;
    q0 += r.x*r.x; q1 += r.y*r.y; q2 += r.z*r.z; q3 += r.w*r.w;
  }
  atomicAdd(&sbn[fo+0], s0); atomicAdd(&sbn[fo+1], s1);
  atomicAdd(&sbn[fo+2], s2); atomicAdd(&sbn[fo+3], s3);
  atomicAdd(&sbn[256+fo+0], q0); atomicAdd(&sbn[256+fo+1], q1);
  atomicAdd(&sbn[256+fo+2], q2); atomicAdd(&sbn[256+fo+3], q3);
  __syncthreads();
  atomicAdd(&bnsum[t], sbn[t]);
  atomicAdd(&bnsq[t],  sbn[256+t]);
}

// bnprep for layer1 + zero ssrc/sdst (for gemm2's dots) + zero bns2
__global__ __launch_bounds__(256) void k_bnprep1x(const float* __restrict__ g, const float* __restrict__ be,
                                                  float* __restrict__ bsum, float* __restrict__ bsq,
                                                  float* __restrict__ ssrc, float* __restrict__ sdst,
                                                  float* __restrict__ bns2){
  const int bid = blockIdx.x, t = threadIdx.x;
  if (bid == 0){
    const float mean = bsum[t] * (1.0f/N_);
    const float var  = bsq[t]  * (1.0f/N_) - mean*mean;
    const float sc = g[t] / sqrtf(var + EPSV);
    bsum[t] = sc;
    bsq[t]  = be[t] - mean*sc;
  }
  if (bid == 1){ bns2[t] = 0.f; bns2[t+256] = 0.f; }
  const int idx = bid*256 + t;
  if (idx < N_){ ssrc[idx] = 0.f; sdst[idx] = 0.f; }
}

// bnprep for layer2 + zero pooled
__global__ __launch_bounds__(256) void k_bnprep2x(const float* __restrict__ g, const float* __restrict__ be,
                                                  float* __restrict__ bsum, float* __restrict__ bsq,
                                                  float* __restrict__ pooled){
  const int bid = blockIdx.x, t = threadIdx.x;
  if (bid == 0){
    const float mean = bsum[t] * (1.0f/N_);
    const float var  = bsq[t]  * (1.0f/N_) - mean*mean;
    const float sc = g[t] / sqrtf(var + EPSV);
    bsum[t] = sc;
    bsq[t]  = be[t] - mean*sc;
  } else {
    const int idx = (bid-1)*256 + t;
    if (idx < G_*256 + G_) pooled[idx] = 0.f;
  }
}

// ---------------- global mean pool (fused BN2+relu), bf16 input ----------------
__global__ __launch_bounds__(256) void k_pool(const unsigned short* __restrict__ x, const int* __restrict__ batch,
                                              const float* __restrict__ sc, const float* __restrict__ sh,
                                              float* __restrict__ psum, float* __restrict__ pcnt){
  const int f = threadIdx.x;
  const float scf = sc[f], shf = sh[f];
  const int RPB = (N_ + gridDim.x - 1) / gridDim.x;
  const int r0 = blockIdx.x * RPB;
  const int r1 = min(r0 + RPB, N_);
  if (r0 >= N_) return;
  float local = 0.f, c = 0.f;
  int curg = -1;
  for (int r = r0; r < r1; ++r){
    const int g = batch[r];
    if (g != curg){
      if (curg >= 0){
        atomicAdd(&psum[curg*256 + f], local);
        if (f == 0) atomicAdd(&pcnt[curg], c);
      }
      curg = g; local = 0.f; c = 0.f;
    }
    local += fmaxf(bf2f(x[(size_t)r*256 + f])*scf + shf, 0.f);
    c += 1.f;
  }
  if (curg >= 0){
    atomicAdd(&psum[curg*256 + f], local);
    if (f == 0) atomicAdd(&pcnt[curg], c);
  }
}

// ---------------- FC head ----------------
__global__ __launch_bounds__(256) void k_fc1(const float* __restrict__ psum, const float* __restrict__ pcnt,
                                             const float* __restrict__ w, const float* __restrict__ b,
                                             float* __restrict__ z){
  __shared__ float p[256];
  const int g = blockIdx.x, f = threadIdx.x;
  const float cnt = fmaxf(pcnt[g], 1.f);
  p[f] = psum[g*256 + f] / cnt;
  __syncthreads();
  float acc = b[f];
  #pragma unroll 8
  for (int k = 0; k < 256; ++k) acc += p[k] * w[k*256 + f];
  z[g*256 + f] = fmaxf(acc, 0.f);
}

__global__ __launch_bounds__(128) void k_fc2(const float* __restrict__ zin, const float* __restrict__ w,
                                             const float* __restrict__ b, float* __restrict__ z){
  __shared__ float p[256];
  const int g = blockIdx.x, f = threadIdx.x;
  p[f] = zin[g*256 + f];
  p[f+128] = zin[g*256 + f + 128];
  __syncthreads();
  float acc = b[f];
  #pragma unroll 8
  for (int k = 0; k < 256; ++k) acc += p[k] * w[k*128 + f];
  z[g*128 + f] = fmaxf(acc, 0.f);
}

__global__ __launch_bounds__(64) void k_fc3(const float* __restrict__ zin, const float* __restrict__ w,
                                            const float* __restrict__ b, float* __restrict__ out){
  const int g = threadIdx.x;   // 64 graphs
  float acc = b[0];
  #pragma unroll 8
  for (int k = 0; k < 128; ++k) acc += zin[g*128 + k] * w[k];
  out[g] = acc;
}

// ---------------- launch ----------------
extern "C" void kernel_launch(void* const* d_in, const int* in_sizes, int n_in,
                              void* d_out, int out_size, void* d_ws, size_t ws_size,
                              hipStream_t stream){
  (void)in_sizes; (void)n_in; (void)out_size; (void)ws_size;
  const float* x    = (const float*)d_in[0];
  const float* W1   = (const float*)d_in[1];
  const float* a_s1 = (const float*)d_in[2];
  const float* a_d1 = (const float*)d_in[3];
  const float* b1   = (const float*)d_in[4];
  const float* g1   = (const float*)d_in[5];
  const float* be1  = (const float*)d_in[6];
  const float* W2   = (const float*)d_in[7];
  const float* a_s2 = (const float*)d_in[8];
  const float* a_d2 = (const float*)d_in[9];
  const float* b2   = (const float*)d_in[10];
  const float* g2   = (const float*)d_in[11];
  const float* be2  = (const float*)d_in[12];
  const float* fc1w = (const float*)d_in[13];
  const float* fc1b = (const float*)d_in[14];
  const float* fc2w = (const float*)d_in[15];
  const float* fc2b = (const float*)d_in[16];
  const float* fc3w = (const float*)d_in[17];
  const float* fc3b = (const float*)d_in[18];
  const int*   ei   = (const int*)d_in[19];
  const int*   batch= (const int*)d_in[20];
  float* out = (float*)d_out;

  char* ws = (char*)d_ws;
  size_t off = 0;
  auto alloc = [&](size_t bytes)->char*{
    char* p = ws + off;
    off += (bytes + 255) & ~(size_t)255;
    return p;
  };
  unsigned short* hb  = (unsigned short*)alloc((size_t)N_*256*2);
  unsigned short* agg = (unsigned short*)alloc((size_t)N_*256*2);   // bf16 agg output
  uint2* staging= (uint2*)alloc((size_t)NBKT*SLAB*8);   // 32.1 MB slabs
  int*   col    = (int*)  alloc((size_t)(E_+N_)*4);
  int*   rowp   = (int*)  alloc((size_t)(N_+1)*4);
  int*   bcnt   = (int*)  alloc(NBKT*4);
  int*   bpre   = (int*)  alloc(NBKT*4);
  unsigned short* wt_hi = (unsigned short*)alloc(256*256*2);
  unsigned short* wt_lo = (unsigned short*)alloc(256*256*2);
  float* ssrc   = (float*)alloc((size_t)N_*4);
  float* sdst   = (float*)alloc((size_t)N_*4);
  float* bns1   = (float*)alloc(512*4);
  float* bns2   = (float*)alloc(512*4);
  float* pooled = (float*)alloc((G_*256 + G_)*4);
  float* z1     = (float*)alloc(G_*256*4);
  float* z2     = (float*)alloc(G_*128*4);

  // ---- init: W2 split + zero ssrc/sdst/bns1/bcnt (391 blocks covers N) ----
  k_init<<<(N_+255)/256, 256, 0, stream>>>(W2, wt_hi, wt_lo, ssrc, sdst, bns1, bcnt);

  // ---- K1: gemm1 part A + slab partition ----
  k_g1_pb<<<G1N + PBBN, 256, 0, stream>>>(x, W1, hb, a_s1, a_d1, ssrc, sdst, ei, bcnt, staging);

  // ---- slab prefix ----
  k_bscan<<<1, 256, 0, stream>>>(bcnt, bpre);

  // ---- K2: gemm1 part B + per-bucket counting sort (rowp + col) ----
  k_g1_pc<<<G2N + NBKT, 256, 0, stream>>>(x, W1, hb, a_s1, a_d1, ssrc, sdst, staging, bcnt, bpre, rowp, col);

  // ---- layer 1 aggregation (+BN1 stats) ----
  k_agg<<<2048, 256, 0, stream>>>(hb, col, rowp, ssrc, sdst, b1, agg, bns1, bns1 + 256);
  k_bnprep1x<<<(N_+255)/256, 256, 0, stream>>>(g1, be1, bns1, bns1 + 256, ssrc, sdst, bns2);

  // ---- layer 2: bf16 MFMA GEMM (BN1+relu fused on A-load; 2-product W split) ----
  k_gemm2_mfma<<<NMT, 256, 0, stream>>>(agg, wt_hi, wt_lo, hb, a_s2, a_d2, ssrc, sdst, bns1, bns1 + 256);
  k_agg<<<2048, 256, 0, stream>>>(hb, col, rowp, ssrc, sdst, b2, agg, bns2, bns2 + 256);
  k_bnprep2x<<<66, 256, 0, stream>>>(g2, be2, bns2, bns2 + 256, pooled);

  // ---- pool (BN2+relu fused, bf16 in) + head ----
  k_pool<<<512, 256, 0, stream>>>(agg, batch, bns2, bns2 + 256, pooled, pooled + G_*256);
  k_fc1<<<G_, 256, 0, stream>>>(pooled, pooled + G_*256, fc1w, fc1b, z1);
  k_fc2<<<G_, 128, 0, stream>>>(z1, fc2w, fc2b, z2);
  k_fc3<<<1, 64, 0, stream>>>(z2, fc3w, fc3b, out);
}